// Round 7
// baseline (287.065 us; speedup 1.0000x reference)
//
#include <hip/hip_runtime.h>

#define DH 64
#define DIN 32
#define BSH 9                 // bucket = dst >> 9 (512-node ranges)
#define BNODES 512
#define MAXB 1024
#define CAPSH 14              // per-bucket capacity 16384 (avg fill ~8.2k, sigma ~90)
#define CAP (1 << CAPSH)

typedef unsigned short u16;
typedef unsigned int u32;

__device__ __forceinline__ float u2lo(u32 u) {   // low bf16 of dword -> f32
    union { u32 i; float f; } x; x.i = u << 16; return x.f;
}
__device__ __forceinline__ float u2hi(u32 u) {   // high bf16 of dword -> f32
    union { u32 i; float f; } x; x.i = u & 0xffff0000u; return x.f;
}
__device__ __forceinline__ u16 f2bf(float f) {
    union { float f; u32 i; } x; x.f = f;
    u32 r = x.i + 0x7fff + ((x.i >> 16) & 1);    // round-to-nearest-even
    return (u16)(r >> 16);
}

// bin packed (src<<BSH | local_dst) into fixed-capacity bucket spans with
// per-(block,bucket) private sub-spans -> partial lines assembled in one L2 each.
// Edge layout (int32 vs int64) detected inline by wave 0.
__global__ void __launch_bounds__(256) binA_k(
        const int* __restrict__ ei, int* __restrict__ gcnt,
        u32* __restrict__ pairs, int E, int n, int nbuck) {
    __shared__ int lhist[MAXB];
    __shared__ int lbase[MAXB];
    __shared__ int smode;
    int t = threadIdx.x;
    if (t < 64) {   // int64 layout: odd 32-bit words are zero high-words
        int v = (2 * t + 1 < 2 * E) ? ei[2 * t + 1] : 0;
        unsigned long long b = __ballot(v != 0);
        if (t == 0) smode = (b != 0ULL) ? 1 : 0;
    }
    for (int b = t; b < nbuck; b += 256) lhist[b] = 0;
    __syncthreads();
    int m = smode;
    const int* srcp = ei;
    const int* dstp = m ? (ei + E) : (ei + 2 * E);
    int stride = m ? 1 : 2;
    int chunk = (E + gridDim.x - 1) / gridDim.x;
    int lo = blockIdx.x * chunk;
    int hi = lo + chunk; if (hi > E) hi = E;
    for (int e = lo + t; e < hi; e += 256) {
        int d = dstp[(size_t)e * stride];
        if ((unsigned)d < (unsigned)n) atomicAdd(&lhist[d >> BSH], 1);
    }
    __syncthreads();
    for (int b = t; b < nbuck; b += 256) {
        int c = lhist[b];
        lbase[b] = c ? ((b << CAPSH) + atomicAdd(&gcnt[b], c)) : 0;
        lhist[b] = 0;                       // reuse as local cursor
    }
    __syncthreads();
    for (int e = lo + t; e < hi; e += 256) {
        int d = dstp[(size_t)e * stride];
        if ((unsigned)d >= (unsigned)n) continue;
        int s = srcp[(size_t)e * stride];
        if ((unsigned)s >= (unsigned)n) s = 0;
        int b = d >> BSH;
        int off = atomicAdd(&lhist[b], 1);
        int pos = lbase[b] + off;
        if (pos < ((b + 1) << CAPSH))       // capacity guard (never hit for uniform dst)
            pairs[pos] = ((u32)s << BSH) | (u32)(d & (BNODES - 1));
    }
}

// one block per bucket: LDS per-node histogram + scan -> rstart/rend/dinv, fill col
__global__ void __launch_bounds__(256) csr_bucket_k(
        const u32* __restrict__ pairs, const int* __restrict__ gcnt,
        int* __restrict__ rstart, int* __restrict__ rend,
        int* __restrict__ col, float* __restrict__ dinv, int N) {
    __shared__ int cnt[BNODES];
    __shared__ int s[256];
    int b = blockIdx.x, t = threadIdx.x;
    int base = b << CAPSH;
    int ec = gcnt[b]; if (ec > CAP) ec = CAP;
    int end = base + ec;
    cnt[t] = 0; cnt[t + 256] = 0;
    __syncthreads();
    for (int i = base + t; i < end; i += 256)
        atomicAdd(&cnt[pairs[i] & (BNODES - 1)], 1);
    __syncthreads();
    int v0 = cnt[2 * t], v1 = cnt[2 * t + 1];
    int tot = v0 + v1;
    s[t] = tot;
    __syncthreads();
    for (int off = 1; off < 256; off <<= 1) {
        int x = (t >= off) ? s[t - off] : 0;
        __syncthreads();
        s[t] += x;
        __syncthreads();
    }
    int excl = s[t] - tot;
    int a0 = base + excl, a1 = a0 + v0;
    int n0 = (b << BSH) + 2 * t, n1 = n0 + 1;
    if (n0 < N) { rstart[n0] = a0; rend[n0] = a1;      dinv[n0] = rsqrtf((float)v0 + 1.0f); }
    if (n1 < N) { rstart[n1] = a1; rend[n1] = a1 + v1; dinv[n1] = rsqrtf((float)v1 + 1.0f); }
    cnt[2 * t] = a0; cnt[2 * t + 1] = a1;
    __syncthreads();
    for (int i = base + t; i < end; i += 256) {
        u32 p = pairs[i];
        int pos = atomicAdd(&cnt[p & (BNODES - 1)], 1);
        col[pos] = (int)(p >> BSH);
    }
}

// h1' = (x @ W1) * dinv[node], bf16 out; 16 nodes/block, wave = 4 nodes x 16 lanes x 4 cols
__global__ void __launch_bounds__(256) gemm1_k(
        const float* __restrict__ x, const float* __restrict__ W1,
        const float* __restrict__ dinv, u16* __restrict__ hp, int n) {
    __shared__ float Wl[DIN * DH];
    __shared__ float xl[16][DIN + 4];
    int tid = threadIdx.x;
    {
        const float4* Wv = (const float4*)W1;
        float4* Wd = (float4*)Wl;
        Wd[tid] = Wv[tid];
        Wd[tid + 256] = Wv[tid + 256];
    }
    if (tid < 128) {
        int idx = tid * 4;
        int row = idx / DIN, ck = idx % DIN;
        float4 v = {0.f, 0.f, 0.f, 0.f};
        if (blockIdx.x * 16 + row < n)
            v = *(const float4*)&x[(size_t)blockIdx.x * 16 * DIN + idx];
        *(float4*)&xl[row][ck] = v;
    }
    __syncthreads();
    int lane = tid & 63, w = tid >> 6;
    int g = lane >> 4, c = lane & 15;
    int node = blockIdx.x * 16 + w * 4 + g;
    const float* xr = xl[w * 4 + g];
    float4 acc = {0.f, 0.f, 0.f, 0.f};
    #pragma unroll
    for (int k = 0; k < DIN; k++) {
        float xv = xr[k];
        float4 wv = *(const float4*)&Wl[k * DH + c * 4];
        acc.x += xv * wv.x; acc.y += xv * wv.y; acc.z += xv * wv.z; acc.w += xv * wv.w;
    }
    if (node < n) {
        float di = dinv[node];
        ushort4 o;
        o.x = f2bf(acc.x * di); o.y = f2bf(acc.y * di);
        o.z = f2bf(acc.z * di); o.w = f2bf(acc.w * di);
        *(ushort4*)&hp[(size_t)node * DH + c * 4] = o;
    }
}

// h2' = (relu(out1_bf16) @ W2) * dinv[node], bf16 out
__global__ void __launch_bounds__(256) gemm2_k(
        const u16* __restrict__ io, const float* __restrict__ W2,
        const float* __restrict__ dinv, u16* __restrict__ hp, int n) {
    __shared__ float Wl[DH * DH];
    __shared__ float xl[16][DH + 4];
    int tid = threadIdx.x;
    {
        const float4* Wv = (const float4*)W2;
        float4* Wd = (float4*)Wl;
        #pragma unroll
        for (int r = 0; r < 4; r++) Wd[tid + 256 * r] = Wv[tid + 256 * r];
    }
    {
        int idx = tid * 4;
        int row = idx / DH, ck = idx % DH;
        float4 v = {0.f, 0.f, 0.f, 0.f};
        if (blockIdx.x * 16 + row < n) {
            ushort4 u = *(const ushort4*)&io[(size_t)blockIdx.x * 16 * DH + idx];
            u32 p0 = ((u32)u.y << 16) | u.x;   // not used; convert individually below
            (void)p0;
            v.x = fmaxf(u2lo(((u32)u.y << 16) | u.x), 0.f);
            v.y = fmaxf(u2hi(((u32)u.y << 16) | u.x), 0.f);
            v.z = fmaxf(u2lo(((u32)u.w << 16) | u.z), 0.f);
            v.w = fmaxf(u2hi(((u32)u.w << 16) | u.z), 0.f);
        }
        *(float4*)&xl[row][ck] = v;
    }
    __syncthreads();
    int lane = tid & 63, w = tid >> 6;
    int g = lane >> 4, c = lane & 15;
    int node = blockIdx.x * 16 + w * 4 + g;
    const float* xr = xl[w * 4 + g];
    float4 acc = {0.f, 0.f, 0.f, 0.f};
    #pragma unroll
    for (int k = 0; k < DH; k++) {
        float xv = xr[k];
        float4 wv = *(const float4*)&Wl[k * DH + c * 4];
        acc.x += xv * wv.x; acc.y += xv * wv.y; acc.z += xv * wv.z; acc.w += xv * wv.w;
    }
    if (node < n) {
        float di = dinv[node];
        ushort4 o;
        o.x = f2bf(acc.x * di); o.y = f2bf(acc.y * di);
        o.z = f2bf(acc.z * di); o.w = f2bf(acc.w * di);
        *(ushort4*)&hp[(size_t)node * DH + c * 4] = o;
    }
}

// edge-sum core, 8-lane groups x uint4: wave = 1 node; g=lane>>3 (edge slot),
// c=lane&7 (cols c*8..c*8+7, 16B). One load instr serves 8 edges (1KB/wave).
// After xor-reduce over masks 8/16/32, EVERY lane holds full sums for its c.
#define EDGE_BODY(SV)                                              \
    {                                                              \
        const uint4 v = *(const uint4*)&hp[(size_t)(SV) * DH + c * 8]; \
        acc[0] += u2lo(v.x); acc[1] += u2hi(v.x);                  \
        acc[2] += u2lo(v.y); acc[3] += u2hi(v.y);                  \
        acc[4] += u2lo(v.z); acc[5] += u2hi(v.z);                  \
        acc[6] += u2lo(v.w); acc[7] += u2hi(v.w);                  \
    }

__device__ __forceinline__ void edge_sum8(const u16* __restrict__ hp,
                                          const int* __restrict__ col,
                                          int start, int end, int lane,
                                          int g, int c, float* acc) {
    int base = start;
    for (; base + 64 <= end; base += 64) {
        int cb = col[base + lane];
        #pragma unroll
        for (int jj = 0; jj < 64; jj += 8) {
            int sv = __shfl(cb, jj + g, 64);
            EDGE_BODY(sv)
        }
    }
    int rem = end - base;
    if (rem > 0) {
        int cb = (lane < rem) ? col[base + lane] : 0;
        for (int jj = 0; jj < rem; jj += 8) {
            int e = jj + g;
            int sv = __shfl(cb, e, 64);
            if (e < rem) EDGE_BODY(sv)
        }
    }
    #pragma unroll
    for (int m = 8; m <= 32; m <<= 1) {
        #pragma unroll
        for (int k = 0; k < 8; k++) acc[k] += __shfl_xor(acc[k], m, 64);
    }
}

// out1[d] = (h'[d] + sum_neighbors) * dinv[d] + bias  -> bf16
__global__ void __launch_bounds__(256) agg_mid_k(
        const u16* __restrict__ hp, const int* __restrict__ rstart,
        const int* __restrict__ rend, const int* __restrict__ col,
        const float* __restrict__ dinv, const float* __restrict__ bias,
        u16* __restrict__ out, int N) {
    int lane = threadIdx.x & 63;
    int node = blockIdx.x * 4 + (threadIdx.x >> 6);
    if (node >= N) return;
    int start = __builtin_amdgcn_readfirstlane(rstart[node]);
    int end   = __builtin_amdgcn_readfirstlane(rend[node]);
    int g = lane >> 3, c = lane & 7;
    float acc[8] = {0.f, 0.f, 0.f, 0.f, 0.f, 0.f, 0.f, 0.f};
    edge_sum8(hp, col, start, end, lane, g, c, acc);
    if (g == 0) {
        uint4 sv = *(const uint4*)&hp[(size_t)node * DH + c * 8];
        float di = dinv[node];
        float4 b0 = *(const float4*)&bias[c * 8];
        float4 b1 = *(const float4*)&bias[c * 8 + 4];
        float o0 = (acc[0] + u2lo(sv.x)) * di + b0.x;
        float o1 = (acc[1] + u2hi(sv.x)) * di + b0.y;
        float o2 = (acc[2] + u2lo(sv.y)) * di + b0.z;
        float o3 = (acc[3] + u2hi(sv.y)) * di + b0.w;
        float o4 = (acc[4] + u2lo(sv.z)) * di + b1.x;
        float o5 = (acc[5] + u2hi(sv.z)) * di + b1.y;
        float o6 = (acc[6] + u2lo(sv.w)) * di + b1.z;
        float o7 = (acc[7] + u2hi(sv.w)) * di + b1.w;
        uint4 po;
        po.x = ((u32)f2bf(o1) << 16) | f2bf(o0);
        po.y = ((u32)f2bf(o3) << 16) | f2bf(o2);
        po.z = ((u32)f2bf(o5) << 16) | f2bf(o4);
        po.w = ((u32)f2bf(o7) << 16) | f2bf(o6);
        *(uint4*)&out[(size_t)node * DH + c * 8] = po;
    }
}

// fused layer-2 aggregation + head: y = sigmoid(relu(out2) . Wo + bo)
__global__ void __launch_bounds__(256) agg_head_k(
        const u16* __restrict__ hp, const int* __restrict__ rstart,
        const int* __restrict__ rend, const int* __restrict__ col,
        const float* __restrict__ dinv, const float* __restrict__ bias,
        const float* __restrict__ Wo, const float* __restrict__ bo,
        float* __restrict__ y, int N) {
    int lane = threadIdx.x & 63;
    int node = blockIdx.x * 4 + (threadIdx.x >> 6);
    if (node >= N) return;
    int start = __builtin_amdgcn_readfirstlane(rstart[node]);
    int end   = __builtin_amdgcn_readfirstlane(rend[node]);
    int g = lane >> 3, c = lane & 7;
    float acc[8] = {0.f, 0.f, 0.f, 0.f, 0.f, 0.f, 0.f, 0.f};
    edge_sum8(hp, col, start, end, lane, g, c, acc);
    if (g == 0) {
        uint4 sv = *(const uint4*)&hp[(size_t)node * DH + c * 8];
        float di = dinv[node];
        float4 b0 = *(const float4*)&bias[c * 8];
        float4 b1 = *(const float4*)&bias[c * 8 + 4];
        float4 w0 = *(const float4*)&Wo[c * 8];
        float4 w1 = *(const float4*)&Wo[c * 8 + 4];
        float t = fmaxf((acc[0] + u2lo(sv.x)) * di + b0.x, 0.f) * w0.x
                + fmaxf((acc[1] + u2hi(sv.x)) * di + b0.y, 0.f) * w0.y
                + fmaxf((acc[2] + u2lo(sv.y)) * di + b0.z, 0.f) * w0.z
                + fmaxf((acc[3] + u2hi(sv.y)) * di + b0.w, 0.f) * w0.w
                + fmaxf((acc[4] + u2lo(sv.z)) * di + b1.x, 0.f) * w1.x
                + fmaxf((acc[5] + u2hi(sv.z)) * di + b1.y, 0.f) * w1.y
                + fmaxf((acc[6] + u2lo(sv.w)) * di + b1.z, 0.f) * w1.z
                + fmaxf((acc[7] + u2hi(sv.w)) * di + b1.w, 0.f) * w1.w;
        #pragma unroll
        for (int m = 1; m < 8; m <<= 1) t += __shfl_xor(t, m, 64);
        if (c == 0) {
            float z = t + bo[0];
            y[node] = 1.f / (1.f + __expf(-z));
        }
    }
}

extern "C" void kernel_launch(void* const* d_in, const int* in_sizes, int n_in,
                              void* d_out, int out_size, void* d_ws, size_t ws_size,
                              hipStream_t stream) {
    const float* x  = (const float*)d_in[0];
    const int*   ei = (const int*)d_in[1];
    const float* W1 = (const float*)d_in[2];
    const float* b1 = (const float*)d_in[3];
    const float* W2 = (const float*)d_in[4];
    const float* b2 = (const float*)d_in[5];
    const float* Wo = (const float*)d_in[6];
    const float* bo = (const float*)d_in[7];
    float* y = (float*)d_out;

    int N = in_sizes[0] / DIN;
    int E = in_sizes[1] / 2;
    int nbuck = ((N - 1) >> BSH) + 1;            // 196 for N=100k (<= MAXB)

    char* ws = (char*)d_ws;
    size_t off = 0;
    auto alloc = [&](size_t bytes) { char* p = ws + off; off += (bytes + 255) & ~(size_t)255; return p; };
    int*   gcnt   = (int*)alloc(MAXB * 4);
    int*   rstart = (int*)alloc((size_t)N * 4);
    int*   rend   = (int*)alloc((size_t)N * 4);
    float* dinv   = (float*)alloc((size_t)N * 4);
    int*   col    = (int*)alloc(((size_t)nbuck << CAPSH) * 4);   // 12.8 MB
    size_t pair_b = ((size_t)nbuck << CAPSH) * 4;
    size_t hp_b   = (size_t)N * DH * 2;
    char*  bufA   = (char*)alloc(pair_b > hp_b ? pair_b : hp_b); // pairs / hp alias
    u16*   bufB   = (u16*)alloc(hp_b);                           // out1 bf16
    u16*   hp    = (u16*)bufA;
    u32*   pairs = (u32*)bufA;   // pairs dead before gemm1 writes hp

    int gN4  = (N + 3) / 4;
    int gN16 = (N + 15) / 16;

    hipMemsetAsync(gcnt, 0, (size_t)nbuck * 4, stream);
    binA_k<<<256, 256, 0, stream>>>(ei, gcnt, pairs, E, N, nbuck);
    csr_bucket_k<<<nbuck, 256, 0, stream>>>(pairs, gcnt, rstart, rend, col, dinv, N);

    // layer 1
    gemm1_k<<<gN16, 256, 0, stream>>>(x, W1, dinv, hp, N);
    agg_mid_k<<<gN4, 256, 0, stream>>>(hp, rstart, rend, col, dinv, b1, bufB, N);

    // layer 2 + fused head
    gemm2_k<<<gN16, 256, 0, stream>>>(bufB, W2, dinv, hp, N);
    agg_head_k<<<gN4, 256, 0, stream>>>(hp, rstart, rend, col, dinv, b2, Wo, bo, y, N);
}

// Round 8
// 261.993 us; speedup vs baseline: 1.0957x; 1.0957x over previous
//
#include <hip/hip_runtime.h>

#define DH 64
#define DIN 32
#define BSH 9                 // bucket = dst >> 9 (512-node ranges)
#define BNODES 512
#define MAXB 1024
#define CAPSH 14              // per-bucket capacity 16384 (avg fill ~8.2k, sigma ~90)
#define CAP (1 << CAPSH)

typedef unsigned short u16;
typedef unsigned int u32;

__device__ __forceinline__ float bf2f(u16 u) {
    union { u32 i; float f; } x; x.i = ((u32)u) << 16; return x.f;
}
__device__ __forceinline__ u16 f2bf(float f) {
    union { float f; u32 i; } x; x.f = f;
    u32 r = x.i + 0x7fff + ((x.i >> 16) & 1);    // round-to-nearest-even
    return (u16)(r >> 16);
}

// bin packed (src<<BSH | local_dst) into fixed-capacity bucket spans with
// per-(block,bucket) private sub-spans -> partial lines assembled in one L2 each.
// Edge layout (int32 vs int64) detected inline by wave 0.
__global__ void __launch_bounds__(256) binA_k(
        const int* __restrict__ ei, int* __restrict__ gcnt,
        u32* __restrict__ pairs, int E, int n, int nbuck) {
    __shared__ int lhist[MAXB];
    __shared__ int lbase[MAXB];
    __shared__ int smode;
    int t = threadIdx.x;
    if (t < 64) {   // int64 layout: odd 32-bit words are zero high-words
        int v = (2 * t + 1 < 2 * E) ? ei[2 * t + 1] : 0;
        unsigned long long b = __ballot(v != 0);
        if (t == 0) smode = (b != 0ULL) ? 1 : 0;
    }
    for (int b = t; b < nbuck; b += 256) lhist[b] = 0;
    __syncthreads();
    int m = smode;
    const int* srcp = ei;
    const int* dstp = m ? (ei + E) : (ei + 2 * E);
    int stride = m ? 1 : 2;
    int chunk = (E + gridDim.x - 1) / gridDim.x;
    int lo = blockIdx.x * chunk;
    int hi = lo + chunk; if (hi > E) hi = E;
    for (int e = lo + t; e < hi; e += 256) {
        int d = dstp[(size_t)e * stride];
        if ((unsigned)d < (unsigned)n) atomicAdd(&lhist[d >> BSH], 1);
    }
    __syncthreads();
    for (int b = t; b < nbuck; b += 256) {
        int c = lhist[b];
        lbase[b] = c ? ((b << CAPSH) + atomicAdd(&gcnt[b], c)) : 0;
        lhist[b] = 0;                       // reuse as local cursor
    }
    __syncthreads();
    for (int e = lo + t; e < hi; e += 256) {
        int d = dstp[(size_t)e * stride];
        if ((unsigned)d >= (unsigned)n) continue;
        int s = srcp[(size_t)e * stride];
        if ((unsigned)s >= (unsigned)n) s = 0;
        int b = d >> BSH;
        int off = atomicAdd(&lhist[b], 1);
        int pos = lbase[b] + off;
        if (pos < ((b + 1) << CAPSH))       // capacity guard (never hit for uniform dst)
            pairs[pos] = ((u32)s << BSH) | (u32)(d & (BNODES - 1));
    }
}

// one block per bucket: LDS per-node histogram + scan -> rstart/rend/dinv, fill col
__global__ void __launch_bounds__(256) csr_bucket_k(
        const u32* __restrict__ pairs, const int* __restrict__ gcnt,
        int* __restrict__ rstart, int* __restrict__ rend,
        int* __restrict__ col, float* __restrict__ dinv, int N) {
    __shared__ int cnt[BNODES];
    __shared__ int s[256];
    int b = blockIdx.x, t = threadIdx.x;
    int base = b << CAPSH;
    int ec = gcnt[b]; if (ec > CAP) ec = CAP;
    int end = base + ec;
    cnt[t] = 0; cnt[t + 256] = 0;
    __syncthreads();
    for (int i = base + t; i < end; i += 256)
        atomicAdd(&cnt[pairs[i] & (BNODES - 1)], 1);
    __syncthreads();
    int v0 = cnt[2 * t], v1 = cnt[2 * t + 1];
    int tot = v0 + v1;
    s[t] = tot;
    __syncthreads();
    for (int off = 1; off < 256; off <<= 1) {
        int x = (t >= off) ? s[t - off] : 0;
        __syncthreads();
        s[t] += x;
        __syncthreads();
    }
    int excl = s[t] - tot;
    int a0 = base + excl, a1 = a0 + v0;
    int n0 = (b << BSH) + 2 * t, n1 = n0 + 1;
    if (n0 < N) { rstart[n0] = a0; rend[n0] = a1;      dinv[n0] = rsqrtf((float)v0 + 1.0f); }
    if (n1 < N) { rstart[n1] = a1; rend[n1] = a1 + v1; dinv[n1] = rsqrtf((float)v1 + 1.0f); }
    cnt[2 * t] = a0; cnt[2 * t + 1] = a1;
    __syncthreads();
    for (int i = base + t; i < end; i += 256) {
        u32 p = pairs[i];
        int pos = atomicAdd(&cnt[p & (BNODES - 1)], 1);
        col[pos] = (int)(p >> BSH);
    }
}

// h1' = (x @ W1) * dinv[node], bf16 out; 16 nodes/block, wave = 4 nodes x 16 lanes x 4 cols
__global__ void __launch_bounds__(256) gemm1_k(
        const float* __restrict__ x, const float* __restrict__ W1,
        const float* __restrict__ dinv, u16* __restrict__ hp, int n) {
    __shared__ float Wl[DIN * DH];
    __shared__ float xl[16][DIN + 4];
    int tid = threadIdx.x;
    {
        const float4* Wv = (const float4*)W1;
        float4* Wd = (float4*)Wl;
        Wd[tid] = Wv[tid];
        Wd[tid + 256] = Wv[tid + 256];
    }
    if (tid < 128) {
        int idx = tid * 4;
        int row = idx / DIN, ck = idx % DIN;
        float4 v = {0.f, 0.f, 0.f, 0.f};
        if (blockIdx.x * 16 + row < n)
            v = *(const float4*)&x[(size_t)blockIdx.x * 16 * DIN + idx];
        *(float4*)&xl[row][ck] = v;
    }
    __syncthreads();
    int lane = tid & 63, w = tid >> 6;
    int g = lane >> 4, c = lane & 15;
    int node = blockIdx.x * 16 + w * 4 + g;
    const float* xr = xl[w * 4 + g];
    float4 acc = {0.f, 0.f, 0.f, 0.f};
    #pragma unroll
    for (int k = 0; k < DIN; k++) {
        float xv = xr[k];
        float4 wv = *(const float4*)&Wl[k * DH + c * 4];
        acc.x += xv * wv.x; acc.y += xv * wv.y; acc.z += xv * wv.z; acc.w += xv * wv.w;
    }
    if (node < n) {
        float di = dinv[node];
        ushort4 o;
        o.x = f2bf(acc.x * di); o.y = f2bf(acc.y * di);
        o.z = f2bf(acc.z * di); o.w = f2bf(acc.w * di);
        *(ushort4*)&hp[(size_t)node * DH + c * 4] = o;
    }
}

// h2' = (relu(out1_bf16) @ W2) * dinv[node], bf16 out
__global__ void __launch_bounds__(256) gemm2_k(
        const u16* __restrict__ io, const float* __restrict__ W2,
        const float* __restrict__ dinv, u16* __restrict__ hp, int n) {
    __shared__ float Wl[DH * DH];
    __shared__ float xl[16][DH + 4];
    int tid = threadIdx.x;
    {
        const float4* Wv = (const float4*)W2;
        float4* Wd = (float4*)Wl;
        #pragma unroll
        for (int r = 0; r < 4; r++) Wd[tid + 256 * r] = Wv[tid + 256 * r];
    }
    {
        int idx = tid * 4;
        int row = idx / DH, ck = idx % DH;
        float4 v = {0.f, 0.f, 0.f, 0.f};
        if (blockIdx.x * 16 + row < n) {
            ushort4 u = *(const ushort4*)&io[(size_t)blockIdx.x * 16 * DH + idx];
            v.x = fmaxf(bf2f(u.x), 0.f); v.y = fmaxf(bf2f(u.y), 0.f);
            v.z = fmaxf(bf2f(u.z), 0.f); v.w = fmaxf(bf2f(u.w), 0.f);
        }
        *(float4*)&xl[row][ck] = v;
    }
    __syncthreads();
    int lane = tid & 63, w = tid >> 6;
    int g = lane >> 4, c = lane & 15;
    int node = blockIdx.x * 16 + w * 4 + g;
    const float* xr = xl[w * 4 + g];
    float4 acc = {0.f, 0.f, 0.f, 0.f};
    #pragma unroll
    for (int k = 0; k < DH; k++) {
        float xv = xr[k];
        float4 wv = *(const float4*)&Wl[k * DH + c * 4];
        acc.x += xv * wv.x; acc.y += xv * wv.y; acc.z += xv * wv.z; acc.w += xv * wv.w;
    }
    if (node < n) {
        float di = dinv[node];
        ushort4 o;
        o.x = f2bf(acc.x * di); o.y = f2bf(acc.y * di);
        o.z = f2bf(acc.z * di); o.w = f2bf(acc.w * di);
        *(ushort4*)&hp[(size_t)node * DH + c * 4] = o;
    }
}

// edge-sum core over bf16 rows (round-6 lean shape, VGPR~16):
// wave = 1 node; g=lane>>4 (edge slot), c=lane&15 (4 cols, 8B ushort4)
__device__ __forceinline__ float4 edge_sum(const u16* __restrict__ hp,
                                           const int* __restrict__ col,
                                           int start, int end, int g, int c) {
    int lane = (g << 4) | c;
    float4 acc = {0.f, 0.f, 0.f, 0.f};
    for (int base = start; base < end; base += 64) {
        int rem = end - base; if (rem > 64) rem = 64;
        int cb = (lane < rem) ? col[base + lane] : 0;
        for (int jj = 0; jj < rem; jj += 8) {
            int e0 = jj + g, e1 = jj + 4 + g;
            int s0 = __shfl(cb, e0, 64);
            int s1 = __shfl(cb, e1, 64);
            bool a0 = e0 < rem, a1 = e1 < rem;
            if (a0) {
                ushort4 v = *(const ushort4*)&hp[(size_t)s0 * DH + c * 4];
                acc.x += bf2f(v.x); acc.y += bf2f(v.y); acc.z += bf2f(v.z); acc.w += bf2f(v.w);
            }
            if (a1) {
                ushort4 v = *(const ushort4*)&hp[(size_t)s1 * DH + c * 4];
                acc.x += bf2f(v.x); acc.y += bf2f(v.y); acc.z += bf2f(v.z); acc.w += bf2f(v.w);
            }
        }
    }
    #pragma unroll
    for (int m = 16; m <= 32; m <<= 1) {
        acc.x += __shfl_xor(acc.x, m, 64);
        acc.y += __shfl_xor(acc.y, m, 64);
        acc.z += __shfl_xor(acc.z, m, 64);
        acc.w += __shfl_xor(acc.w, m, 64);
    }
    return acc;
}

// out1[d] = (h'[d] + sum_neighbors) * dinv[d] + bias  -> bf16
__global__ void __launch_bounds__(256) agg_mid_k(
        const u16* __restrict__ hp, const int* __restrict__ rstart,
        const int* __restrict__ rend, const int* __restrict__ col,
        const float* __restrict__ dinv, const float* __restrict__ bias,
        u16* __restrict__ out, int N) {
    int lane = threadIdx.x & 63;
    int node = blockIdx.x * 4 + (threadIdx.x >> 6);
    if (node >= N) return;
    int start = __builtin_amdgcn_readfirstlane(rstart[node]);
    int end   = __builtin_amdgcn_readfirstlane(rend[node]);
    int g = lane >> 4, c = lane & 15;
    float4 acc = edge_sum(hp, col, start, end, g, c);
    if (g == 0) {
        ushort4 sv = *(const ushort4*)&hp[(size_t)node * DH + c * 4];
        float4 b = *(const float4*)&bias[c * 4];
        float di = dinv[node];
        ushort4 o;
        o.x = f2bf((acc.x + bf2f(sv.x)) * di + b.x);
        o.y = f2bf((acc.y + bf2f(sv.y)) * di + b.y);
        o.z = f2bf((acc.z + bf2f(sv.z)) * di + b.z);
        o.w = f2bf((acc.w + bf2f(sv.w)) * di + b.w);
        *(ushort4*)&out[(size_t)node * DH + c * 4] = o;
    }
}

// fused layer-2 aggregation + head: y = sigmoid(relu(out2) . Wo + bo)
__global__ void __launch_bounds__(256) agg_head_k(
        const u16* __restrict__ hp, const int* __restrict__ rstart,
        const int* __restrict__ rend, const int* __restrict__ col,
        const float* __restrict__ dinv, const float* __restrict__ bias,
        const float* __restrict__ Wo, const float* __restrict__ bo,
        float* __restrict__ y, int N) {
    int lane = threadIdx.x & 63;
    int node = blockIdx.x * 4 + (threadIdx.x >> 6);
    if (node >= N) return;
    int start = __builtin_amdgcn_readfirstlane(rstart[node]);
    int end   = __builtin_amdgcn_readfirstlane(rend[node]);
    int g = lane >> 4, c = lane & 15;
    float4 acc = edge_sum(hp, col, start, end, g, c);
    if (g == 0) {
        ushort4 sv = *(const ushort4*)&hp[(size_t)node * DH + c * 4];
        float4 b = *(const float4*)&bias[c * 4];
        float4 wo = *(const float4*)&Wo[c * 4];
        float di = dinv[node];
        float t = fmaxf((acc.x + bf2f(sv.x)) * di + b.x, 0.f) * wo.x
                + fmaxf((acc.y + bf2f(sv.y)) * di + b.y, 0.f) * wo.y
                + fmaxf((acc.z + bf2f(sv.z)) * di + b.z, 0.f) * wo.z
                + fmaxf((acc.w + bf2f(sv.w)) * di + b.w, 0.f) * wo.w;
        #pragma unroll
        for (int m = 1; m < 16; m <<= 1) t += __shfl_xor(t, m, 64);
        if (c == 0) {
            float z = t + bo[0];
            y[node] = 1.f / (1.f + __expf(-z));
        }
    }
}

extern "C" void kernel_launch(void* const* d_in, const int* in_sizes, int n_in,
                              void* d_out, int out_size, void* d_ws, size_t ws_size,
                              hipStream_t stream) {
    const float* x  = (const float*)d_in[0];
    const int*   ei = (const int*)d_in[1];
    const float* W1 = (const float*)d_in[2];
    const float* b1 = (const float*)d_in[3];
    const float* W2 = (const float*)d_in[4];
    const float* b2 = (const float*)d_in[5];
    const float* Wo = (const float*)d_in[6];
    const float* bo = (const float*)d_in[7];
    float* y = (float*)d_out;

    int N = in_sizes[0] / DIN;
    int E = in_sizes[1] / 2;
    int nbuck = ((N - 1) >> BSH) + 1;            // 196 for N=100k (<= MAXB)

    char* ws = (char*)d_ws;
    size_t off = 0;
    auto alloc = [&](size_t bytes) { char* p = ws + off; off += (bytes + 255) & ~(size_t)255; return p; };
    int*   gcnt   = (int*)alloc(MAXB * 4);
    int*   rstart = (int*)alloc((size_t)N * 4);
    int*   rend   = (int*)alloc((size_t)N * 4);
    float* dinv   = (float*)alloc((size_t)N * 4);
    int*   col    = (int*)alloc(((size_t)nbuck << CAPSH) * 4);   // 12.8 MB
    size_t pair_b = ((size_t)nbuck << CAPSH) * 4;
    size_t hp_b   = (size_t)N * DH * 2;
    char*  bufA   = (char*)alloc(pair_b > hp_b ? pair_b : hp_b); // pairs / hp alias
    u16*   bufB   = (u16*)alloc(hp_b);                           // out1 bf16
    u16*   hp    = (u16*)bufA;
    u32*   pairs = (u32*)bufA;   // pairs dead before gemm1 writes hp

    int gN4  = (N + 3) / 4;
    int gN16 = (N + 15) / 16;

    hipMemsetAsync(gcnt, 0, (size_t)nbuck * 4, stream);
    binA_k<<<256, 256, 0, stream>>>(ei, gcnt, pairs, E, N, nbuck);
    csr_bucket_k<<<nbuck, 256, 0, stream>>>(pairs, gcnt, rstart, rend, col, dinv, N);

    // layer 1
    gemm1_k<<<gN16, 256, 0, stream>>>(x, W1, dinv, hp, N);
    agg_mid_k<<<gN4, 256, 0, stream>>>(hp, rstart, rend, col, dinv, b1, bufB, N);

    // layer 2 + fused head
    gemm2_k<<<gN16, 256, 0, stream>>>(bufB, W2, dinv, hp, N);
    agg_head_k<<<gN4, 256, 0, stream>>>(hp, rstart, rend, col, dinv, b2, Wo, bo, y, N);
}

// Round 9
// 250.521 us; speedup vs baseline: 1.1459x; 1.0458x over previous
//
#include <hip/hip_runtime.h>

#define DH 64
#define DIN 32
#define BSH 8                 // bucket = dst >> 8 (256-node ranges)
#define BNODES 256
#define MAXB 1024
#define CAPSH 13              // per-bucket capacity 8192 (avg fill ~4.1k, sigma ~64)
#define CAP (1 << CAPSH)

typedef unsigned short u16;
typedef unsigned int u32;

__device__ __forceinline__ float bf2f(u16 u) {
    union { u32 i; float f; } x; x.i = ((u32)u) << 16; return x.f;
}
__device__ __forceinline__ u16 f2bf(float f) {
    union { float f; u32 i; } x; x.f = f;
    u32 r = x.i + 0x7fff + ((x.i >> 16) & 1);    // round-to-nearest-even
    return (u16)(r >> 16);
}

// bin packed (src<<BSH | local_dst) into fixed-capacity bucket spans with
// per-(block,bucket) private sub-spans. Grid-stride granules (phase1 and
// phase3 iterate the SAME set per block, contiguity not required).
// Edge layout (int32 vs int64) detected inline by wave 0.
__global__ void __launch_bounds__(256) binA_k(
        const int* __restrict__ ei, int* __restrict__ gcnt,
        u32* __restrict__ pairs, int E, int n, int nbuck) {
    __shared__ int lhist[MAXB];
    __shared__ int lbase[MAXB];
    __shared__ int smode;
    int t = threadIdx.x;
    if (t < 64) {   // int64 layout: odd 32-bit words are zero high-words
        int v = (2 * t + 1 < 2 * E) ? ei[2 * t + 1] : 0;
        unsigned long long b = __ballot(v != 0);
        if (t == 0) smode = (b != 0ULL) ? 1 : 0;
    }
    for (int b = t; b < nbuck; b += 256) lhist[b] = 0;
    __syncthreads();
    int m = smode;
    unsigned un = (unsigned)n;
    int q0 = blockIdx.x * 256 + t;
    int qs = gridDim.x * 256;

    // ---- phase 1: count this block's edges per bucket
    if (m && !(E & 3)) {                       // int32, 4 edges per int4
        const int4* d4 = (const int4*)(ei + E);
        for (int q = q0; q < (E >> 2); q += qs) {
            int4 d = d4[q];
            if ((unsigned)d.x < un) atomicAdd(&lhist[d.x >> BSH], 1);
            if ((unsigned)d.y < un) atomicAdd(&lhist[d.y >> BSH], 1);
            if ((unsigned)d.z < un) atomicAdd(&lhist[d.z >> BSH], 1);
            if ((unsigned)d.w < un) atomicAdd(&lhist[d.w >> BSH], 1);
        }
    } else if (!m && !(E & 1)) {               // int64, 2 edges per int4
        const int4* d4 = (const int4*)(ei + 2 * E);
        for (int q = q0; q < (E >> 1); q += qs) {
            int4 d = d4[q];
            if ((unsigned)d.x < un) atomicAdd(&lhist[d.x >> BSH], 1);
            if ((unsigned)d.z < un) atomicAdd(&lhist[d.z >> BSH], 1);
        }
    } else {
        const int* dstp = m ? (ei + E) : (ei + 2 * E);
        int stride = m ? 1 : 2;
        for (int e = q0; e < E; e += qs) {
            int d = dstp[(size_t)e * stride];
            if ((unsigned)d < un) atomicAdd(&lhist[d >> BSH], 1);
        }
    }
    __syncthreads();
    // ---- phase 2: reserve private spans
    for (int b = t; b < nbuck; b += 256) {
        int c = lhist[b];
        lbase[b] = c ? ((b << CAPSH) + atomicAdd(&gcnt[b], c)) : 0;
        lhist[b] = 0;                          // reuse as local cursor
    }
    __syncthreads();
    // ---- phase 3: scatter into private spans
    #define EMIT(S, D)                                                     \
        if ((unsigned)(D) < un) {                                          \
            int sv = ((unsigned)(S) < un) ? (S) : 0;                       \
            int bb = (D) >> BSH;                                           \
            int off = atomicAdd(&lhist[bb], 1);                            \
            int pos = lbase[bb] + off;                                     \
            if (pos < ((bb + 1) << CAPSH))                                 \
                pairs[pos] = ((u32)sv << BSH) | (u32)((D) & (BNODES - 1)); \
        }
    if (m && !(E & 3)) {
        const int4* s4 = (const int4*)ei;
        const int4* d4 = (const int4*)(ei + E);
        for (int q = q0; q < (E >> 2); q += qs) {
            int4 s = s4[q]; int4 d = d4[q];
            EMIT(s.x, d.x) EMIT(s.y, d.y) EMIT(s.z, d.z) EMIT(s.w, d.w)
        }
    } else if (!m && !(E & 1)) {
        const int4* s4 = (const int4*)ei;
        const int4* d4 = (const int4*)(ei + 2 * E);
        for (int q = q0; q < (E >> 1); q += qs) {
            int4 s = s4[q]; int4 d = d4[q];
            EMIT(s.x, d.x) EMIT(s.z, d.z)
        }
    } else {
        const int* srcp = ei;
        const int* dstp = m ? (ei + E) : (ei + 2 * E);
        int stride = m ? 1 : 2;
        for (int e = q0; e < E; e += qs) {
            int d = dstp[(size_t)e * stride];
            int s = srcp[(size_t)e * stride];
            EMIT(s, d)
        }
    }
    #undef EMIT
}

// one block (512 thr) per bucket: LDS per-node histogram + scan -> rstart/rend/dinv,
// then fill col within the bucket's span (one CU -> one L2, lines assembled in-L2)
__global__ void __launch_bounds__(512) csr_bucket_k(
        const u32* __restrict__ pairs, const int* __restrict__ gcnt,
        int* __restrict__ rstart, int* __restrict__ rend,
        int* __restrict__ col, float* __restrict__ dinv, int N) {
    __shared__ int cnt[BNODES];
    __shared__ int s[BNODES];
    int b = blockIdx.x, t = threadIdx.x;
    int base = b << CAPSH;
    int ec = gcnt[b]; if (ec > CAP) ec = CAP;
    int end = base + ec;
    if (t < BNODES) cnt[t] = 0;
    __syncthreads();
    for (int i = base + t; i < end; i += 512)
        atomicAdd(&cnt[pairs[i] & (BNODES - 1)], 1);
    __syncthreads();
    int v = (t < BNODES) ? cnt[t] : 0;
    if (t < BNODES) s[t] = v;
    __syncthreads();
    for (int off = 1; off < BNODES; off <<= 1) {
        int x = (t >= off && t < BNODES) ? s[t - off] : 0;
        __syncthreads();
        if (t < BNODES) s[t] += x;
        __syncthreads();
    }
    if (t < BNODES) {
        int excl = s[t] - v;
        int a = base + excl;
        int node = (b << BSH) + t;
        if (node < N) {
            rstart[node] = a;
            rend[node]   = a + v;
            dinv[node]   = rsqrtf((float)v + 1.0f);
        }
        cnt[t] = a;                            // cursor
    }
    __syncthreads();
    for (int i = base + t; i < end; i += 512) {
        u32 p = pairs[i];
        int pos = atomicAdd(&cnt[p & (BNODES - 1)], 1);
        col[pos] = (int)(p >> BSH);
    }
}

// h1' = (x @ W1) * dinv[node], bf16 out; 64 nodes/block (4 sub-tiles of 16),
// W1 loaded to LDS once per block
__global__ void __launch_bounds__(256) gemm1_k(
        const float* __restrict__ x, const float* __restrict__ W1,
        const float* __restrict__ dinv, u16* __restrict__ hp, int n) {
    __shared__ float Wl[DIN * DH];           // 8 KB
    __shared__ float xl[16][DIN + 4];
    int tid = threadIdx.x;
    {
        const float4* Wv = (const float4*)W1;
        float4* Wd = (float4*)Wl;
        Wd[tid] = Wv[tid];
        Wd[tid + 256] = Wv[tid + 256];
    }
    int lane = tid & 63, w = tid >> 6;
    int g = lane >> 4, c = lane & 15;
    for (int sub = 0; sub < 4; sub++) {
        int tb = blockIdx.x * 64 + sub * 16;
        __syncthreads();                      // xl reuse guard (also covers W on sub=0)
        if (tid < 128) {
            int idx = tid * 4;
            int row = idx / DIN, ck = idx % DIN;
            float4 v = {0.f, 0.f, 0.f, 0.f};
            if (tb + row < n)
                v = *(const float4*)&x[(size_t)(tb + row) * DIN + ck];
            *(float4*)&xl[row][ck] = v;
        }
        __syncthreads();
        int node = tb + w * 4 + g;
        const float* xr = xl[w * 4 + g];
        float4 acc = {0.f, 0.f, 0.f, 0.f};
        #pragma unroll
        for (int k = 0; k < DIN; k++) {
            float xv = xr[k];
            float4 wv = *(const float4*)&Wl[k * DH + c * 4];
            acc.x += xv * wv.x; acc.y += xv * wv.y; acc.z += xv * wv.z; acc.w += xv * wv.w;
        }
        if (node < n) {
            float di = dinv[node];
            ushort4 o;
            o.x = f2bf(acc.x * di); o.y = f2bf(acc.y * di);
            o.z = f2bf(acc.z * di); o.w = f2bf(acc.w * di);
            *(ushort4*)&hp[(size_t)node * DH + c * 4] = o;
        }
    }
}

// h2' = (relu(out1_bf16) @ W2) * dinv[node], bf16 out; 64 nodes/block
__global__ void __launch_bounds__(256) gemm2_k(
        const u16* __restrict__ io, const float* __restrict__ W2,
        const float* __restrict__ dinv, u16* __restrict__ hp, int n) {
    __shared__ float Wl[DH * DH];            // 16 KB
    __shared__ float xl[16][DH + 4];
    int tid = threadIdx.x;
    {
        const float4* Wv = (const float4*)W2;
        float4* Wd = (float4*)Wl;
        #pragma unroll
        for (int r = 0; r < 4; r++) Wd[tid + 256 * r] = Wv[tid + 256 * r];
    }
    int lane = tid & 63, w = tid >> 6;
    int g = lane >> 4, c = lane & 15;
    for (int sub = 0; sub < 4; sub++) {
        int tb = blockIdx.x * 64 + sub * 16;
        __syncthreads();
        {
            int idx = tid * 4;
            int row = idx / DH, ck = idx % DH;
            float4 v = {0.f, 0.f, 0.f, 0.f};
            if (tb + row < n) {
                ushort4 u = *(const ushort4*)&io[(size_t)(tb + row) * DH + ck];
                v.x = fmaxf(bf2f(u.x), 0.f); v.y = fmaxf(bf2f(u.y), 0.f);
                v.z = fmaxf(bf2f(u.z), 0.f); v.w = fmaxf(bf2f(u.w), 0.f);
            }
            *(float4*)&xl[row][ck] = v;
        }
        __syncthreads();
        int node = tb + w * 4 + g;
        const float* xr = xl[w * 4 + g];
        float4 acc = {0.f, 0.f, 0.f, 0.f};
        #pragma unroll
        for (int k = 0; k < DH; k++) {
            float xv = xr[k];
            float4 wv = *(const float4*)&Wl[k * DH + c * 4];
            acc.x += xv * wv.x; acc.y += xv * wv.y; acc.z += xv * wv.z; acc.w += xv * wv.w;
        }
        if (node < n) {
            float di = dinv[node];
            ushort4 o;
            o.x = f2bf(acc.x * di); o.y = f2bf(acc.y * di);
            o.z = f2bf(acc.z * di); o.w = f2bf(acc.w * di);
            *(ushort4*)&hp[(size_t)node * DH + c * 4] = o;
        }
    }
}

// edge-sum core over bf16 rows (round-8 lean shape, VGPR~16):
// wave = 1 node; g=lane>>4 (edge slot), c=lane&15 (4 cols, 8B ushort4)
__device__ __forceinline__ float4 edge_sum(const u16* __restrict__ hp,
                                           const int* __restrict__ col,
                                           int start, int end, int g, int c) {
    int lane = (g << 4) | c;
    float4 acc = {0.f, 0.f, 0.f, 0.f};
    for (int base = start; base < end; base += 64) {
        int rem = end - base; if (rem > 64) rem = 64;
        int cb = (lane < rem) ? col[base + lane] : 0;
        for (int jj = 0; jj < rem; jj += 8) {
            int e0 = jj + g, e1 = jj + 4 + g;
            int s0 = __shfl(cb, e0, 64);
            int s1 = __shfl(cb, e1, 64);
            bool a0 = e0 < rem, a1 = e1 < rem;
            if (a0) {
                ushort4 v = *(const ushort4*)&hp[(size_t)s0 * DH + c * 4];
                acc.x += bf2f(v.x); acc.y += bf2f(v.y); acc.z += bf2f(v.z); acc.w += bf2f(v.w);
            }
            if (a1) {
                ushort4 v = *(const ushort4*)&hp[(size_t)s1 * DH + c * 4];
                acc.x += bf2f(v.x); acc.y += bf2f(v.y); acc.z += bf2f(v.z); acc.w += bf2f(v.w);
            }
        }
    }
    #pragma unroll
    for (int m = 16; m <= 32; m <<= 1) {
        acc.x += __shfl_xor(acc.x, m, 64);
        acc.y += __shfl_xor(acc.y, m, 64);
        acc.z += __shfl_xor(acc.z, m, 64);
        acc.w += __shfl_xor(acc.w, m, 64);
    }
    return acc;
}

// out1[d] = (h'[d] + sum_neighbors) * dinv[d] + bias  -> bf16
__global__ void __launch_bounds__(256) agg_mid_k(
        const u16* __restrict__ hp, const int* __restrict__ rstart,
        const int* __restrict__ rend, const int* __restrict__ col,
        const float* __restrict__ dinv, const float* __restrict__ bias,
        u16* __restrict__ out, int N) {
    int lane = threadIdx.x & 63;
    int node = blockIdx.x * 4 + (threadIdx.x >> 6);
    if (node >= N) return;
    int start = __builtin_amdgcn_readfirstlane(rstart[node]);
    int end   = __builtin_amdgcn_readfirstlane(rend[node]);
    int g = lane >> 4, c = lane & 15;
    float4 acc = edge_sum(hp, col, start, end, g, c);
    if (g == 0) {
        ushort4 sv = *(const ushort4*)&hp[(size_t)node * DH + c * 4];
        float4 b = *(const float4*)&bias[c * 4];
        float di = dinv[node];
        ushort4 o;
        o.x = f2bf((acc.x + bf2f(sv.x)) * di + b.x);
        o.y = f2bf((acc.y + bf2f(sv.y)) * di + b.y);
        o.z = f2bf((acc.z + bf2f(sv.z)) * di + b.z);
        o.w = f2bf((acc.w + bf2f(sv.w)) * di + b.w);
        *(ushort4*)&out[(size_t)node * DH + c * 4] = o;
    }
}

// fused layer-2 aggregation + head: y = sigmoid(relu(out2) . Wo + bo)
__global__ void __launch_bounds__(256) agg_head_k(
        const u16* __restrict__ hp, const int* __restrict__ rstart,
        const int* __restrict__ rend, const int* __restrict__ col,
        const float* __restrict__ dinv, const float* __restrict__ bias,
        const float* __restrict__ Wo, const float* __restrict__ bo,
        float* __restrict__ y, int N) {
    int lane = threadIdx.x & 63;
    int node = blockIdx.x * 4 + (threadIdx.x >> 6);
    if (node >= N) return;
    int start = __builtin_amdgcn_readfirstlane(rstart[node]);
    int end   = __builtin_amdgcn_readfirstlane(rend[node]);
    int g = lane >> 4, c = lane & 15;
    float4 acc = edge_sum(hp, col, start, end, g, c);
    if (g == 0) {
        ushort4 sv = *(const ushort4*)&hp[(size_t)node * DH + c * 4];
        float4 b = *(const float4*)&bias[c * 4];
        float4 wo = *(const float4*)&Wo[c * 4];
        float di = dinv[node];
        float t = fmaxf((acc.x + bf2f(sv.x)) * di + b.x, 0.f) * wo.x
                + fmaxf((acc.y + bf2f(sv.y)) * di + b.y, 0.f) * wo.y
                + fmaxf((acc.z + bf2f(sv.z)) * di + b.z, 0.f) * wo.z
                + fmaxf((acc.w + bf2f(sv.w)) * di + b.w, 0.f) * wo.w;
        #pragma unroll
        for (int m = 1; m < 16; m <<= 1) t += __shfl_xor(t, m, 64);
        if (c == 0) {
            float z = t + bo[0];
            y[node] = 1.f / (1.f + __expf(-z));
        }
    }
}

extern "C" void kernel_launch(void* const* d_in, const int* in_sizes, int n_in,
                              void* d_out, int out_size, void* d_ws, size_t ws_size,
                              hipStream_t stream) {
    const float* x  = (const float*)d_in[0];
    const int*   ei = (const int*)d_in[1];
    const float* W1 = (const float*)d_in[2];
    const float* b1 = (const float*)d_in[3];
    const float* W2 = (const float*)d_in[4];
    const float* b2 = (const float*)d_in[5];
    const float* Wo = (const float*)d_in[6];
    const float* bo = (const float*)d_in[7];
    float* y = (float*)d_out;

    int N = in_sizes[0] / DIN;
    int E = in_sizes[1] / 2;
    int nbuck = ((N - 1) >> BSH) + 1;            // 391 for N=100k (<= MAXB)

    char* ws = (char*)d_ws;
    size_t off = 0;
    auto alloc = [&](size_t bytes) { char* p = ws + off; off += (bytes + 255) & ~(size_t)255; return p; };
    int*   gcnt   = (int*)alloc(MAXB * 4);
    int*   rstart = (int*)alloc((size_t)N * 4);
    int*   rend   = (int*)alloc((size_t)N * 4);
    float* dinv   = (float*)alloc((size_t)N * 4);
    int*   col    = (int*)alloc(((size_t)nbuck << CAPSH) * 4);   // ~12.8 MB
    size_t pair_b = ((size_t)nbuck << CAPSH) * 4;
    size_t hp_b   = (size_t)N * DH * 2;
    char*  bufA   = (char*)alloc(pair_b > hp_b ? pair_b : hp_b); // pairs / hp alias
    u16*   bufB   = (u16*)alloc(hp_b);                           // out1 bf16
    u16*   hp    = (u16*)bufA;
    u32*   pairs = (u32*)bufA;   // pairs dead before gemm1 writes hp

    int gN4  = (N + 3) / 4;
    int gN64 = (N + 63) / 64;

    hipMemsetAsync(gcnt, 0, (size_t)nbuck * 4, stream);
    binA_k<<<512, 256, 0, stream>>>(ei, gcnt, pairs, E, N, nbuck);
    csr_bucket_k<<<nbuck, 512, 0, stream>>>(pairs, gcnt, rstart, rend, col, dinv, N);

    // layer 1
    gemm1_k<<<gN64, 256, 0, stream>>>(x, W1, dinv, hp, N);
    agg_mid_k<<<gN4, 256, 0, stream>>>(hp, rstart, rend, col, dinv, b1, bufB, N);

    // layer 2 + fused head
    gemm2_k<<<gN64, 256, 0, stream>>>(bufB, W2, dinv, hp, N);
    agg_head_k<<<gN4, 256, 0, stream>>>(hp, rstart, rend, col, dinv, b2, Wo, bo, y, N);
}

// Round 10
// 238.911 us; speedup vs baseline: 1.2016x; 1.0486x over previous
//
#include <hip/hip_runtime.h>

#define DH 64
#define DIN 32
#define BSH 8                 // bucket = dst >> 8 (256-node ranges)
#define BNODES 256
#define MAXB 1024
#define CAPSH 13              // per-bucket capacity 8192 (avg fill ~4.1k, sigma ~64)
#define CAP (1 << CAPSH)

typedef unsigned short u16;
typedef unsigned int u32;

__device__ __forceinline__ float bf2f(u16 u) {
    union { u32 i; float f; } x; x.i = ((u32)u) << 16; return x.f;
}
__device__ __forceinline__ u16 f2bf(float f) {
    union { float f; u32 i; } x; x.f = f;
    u32 r = x.i + 0x7fff + ((x.i >> 16) & 1);    // round-to-nearest-even
    return (u16)(r >> 16);
}

// bin packed (src<<BSH | local_dst) into fixed-capacity bucket spans with
// per-(block,bucket) private sub-spans. Grid-stride granules.
// Edge layout (int32 vs int64) detected inline by wave 0.
__global__ void __launch_bounds__(256) binA_k(
        const int* __restrict__ ei, int* __restrict__ gcnt,
        u32* __restrict__ pairs, int E, int n, int nbuck) {
    __shared__ int lhist[MAXB];
    __shared__ int lbase[MAXB];
    __shared__ int smode;
    int t = threadIdx.x;
    if (t < 64) {   // int64 layout: odd 32-bit words are zero high-words
        int v = (2 * t + 1 < 2 * E) ? ei[2 * t + 1] : 0;
        unsigned long long b = __ballot(v != 0);
        if (t == 0) smode = (b != 0ULL) ? 1 : 0;
    }
    for (int b = t; b < nbuck; b += 256) lhist[b] = 0;
    __syncthreads();
    int m = smode;
    unsigned un = (unsigned)n;
    int q0 = blockIdx.x * 256 + t;
    int qs = gridDim.x * 256;

    // ---- phase 1: count this block's edges per bucket
    if (m && !(E & 3)) {                       // int32, 4 edges per int4
        const int4* d4 = (const int4*)(ei + E);
        for (int q = q0; q < (E >> 2); q += qs) {
            int4 d = d4[q];
            if ((unsigned)d.x < un) atomicAdd(&lhist[d.x >> BSH], 1);
            if ((unsigned)d.y < un) atomicAdd(&lhist[d.y >> BSH], 1);
            if ((unsigned)d.z < un) atomicAdd(&lhist[d.z >> BSH], 1);
            if ((unsigned)d.w < un) atomicAdd(&lhist[d.w >> BSH], 1);
        }
    } else if (!m && !(E & 1)) {               // int64, 2 edges per int4
        const int4* d4 = (const int4*)(ei + 2 * E);
        for (int q = q0; q < (E >> 1); q += qs) {
            int4 d = d4[q];
            if ((unsigned)d.x < un) atomicAdd(&lhist[d.x >> BSH], 1);
            if ((unsigned)d.z < un) atomicAdd(&lhist[d.z >> BSH], 1);
        }
    } else {
        const int* dstp = m ? (ei + E) : (ei + 2 * E);
        int stride = m ? 1 : 2;
        for (int e = q0; e < E; e += qs) {
            int d = dstp[(size_t)e * stride];
            if ((unsigned)d < un) atomicAdd(&lhist[d >> BSH], 1);
        }
    }
    __syncthreads();
    // ---- phase 2: reserve private spans
    for (int b = t; b < nbuck; b += 256) {
        int c = lhist[b];
        lbase[b] = c ? ((b << CAPSH) + atomicAdd(&gcnt[b], c)) : 0;
        lhist[b] = 0;                          // reuse as local cursor
    }
    __syncthreads();
    // ---- phase 3: scatter into private spans
    #define EMIT(S, D)                                                     \
        if ((unsigned)(D) < un) {                                          \
            int sv = ((unsigned)(S) < un) ? (S) : 0;                       \
            int bb = (D) >> BSH;                                           \
            int off = atomicAdd(&lhist[bb], 1);                            \
            int pos = lbase[bb] + off;                                     \
            if (pos < ((bb + 1) << CAPSH))                                 \
                pairs[pos] = ((u32)sv << BSH) | (u32)((D) & (BNODES - 1)); \
        }
    if (m && !(E & 3)) {
        const int4* s4 = (const int4*)ei;
        const int4* d4 = (const int4*)(ei + E);
        for (int q = q0; q < (E >> 2); q += qs) {
            int4 s = s4[q]; int4 d = d4[q];
            EMIT(s.x, d.x) EMIT(s.y, d.y) EMIT(s.z, d.z) EMIT(s.w, d.w)
        }
    } else if (!m && !(E & 1)) {
        const int4* s4 = (const int4*)ei;
        const int4* d4 = (const int4*)(ei + 2 * E);
        for (int q = q0; q < (E >> 1); q += qs) {
            int4 s = s4[q]; int4 d = d4[q];
            EMIT(s.x, d.x) EMIT(s.z, d.z)
        }
    } else {
        const int* srcp = ei;
        const int* dstp = m ? (ei + E) : (ei + 2 * E);
        int stride = m ? 1 : 2;
        for (int e = q0; e < E; e += qs) {
            int d = dstp[(size_t)e * stride];
            int s = srcp[(size_t)e * stride];
            EMIT(s, d)
        }
    }
    #undef EMIT
}

// one block (512 thr) per bucket: LDS per-node histogram + scan -> rstart/rend/dinv,
// then fill col within the bucket's span
__global__ void __launch_bounds__(512) csr_bucket_k(
        const u32* __restrict__ pairs, const int* __restrict__ gcnt,
        int* __restrict__ rstart, int* __restrict__ rend,
        int* __restrict__ col, float* __restrict__ dinv, int N) {
    __shared__ int cnt[BNODES];
    __shared__ int s[BNODES];
    int b = blockIdx.x, t = threadIdx.x;
    int base = b << CAPSH;
    int ec = gcnt[b]; if (ec > CAP) ec = CAP;
    int end = base + ec;
    if (t < BNODES) cnt[t] = 0;
    __syncthreads();
    for (int i = base + t; i < end; i += 512)
        atomicAdd(&cnt[pairs[i] & (BNODES - 1)], 1);
    __syncthreads();
    int v = (t < BNODES) ? cnt[t] : 0;
    if (t < BNODES) s[t] = v;
    __syncthreads();
    for (int off = 1; off < BNODES; off <<= 1) {
        int x = (t >= off && t < BNODES) ? s[t - off] : 0;
        __syncthreads();
        if (t < BNODES) s[t] += x;
        __syncthreads();
    }
    if (t < BNODES) {
        int excl = s[t] - v;
        int a = base + excl;
        int node = (b << BSH) + t;
        if (node < N) {
            rstart[node] = a;
            rend[node]   = a + v;
            dinv[node]   = rsqrtf((float)v + 1.0f);
        }
        cnt[t] = a;                            // cursor
    }
    __syncthreads();
    for (int i = base + t; i < end; i += 512) {
        u32 p = pairs[i];
        int pos = atomicAdd(&cnt[p & (BNODES - 1)], 1);
        col[pos] = (int)(p >> BSH);
    }
}

// h1' = (x @ W1) * dinv[node], bf16 out; 64 nodes/block (4 sub-tiles of 16)
__global__ void __launch_bounds__(256) gemm1_k(
        const float* __restrict__ x, const float* __restrict__ W1,
        const float* __restrict__ dinv, u16* __restrict__ hp, int n) {
    __shared__ float Wl[DIN * DH];           // 8 KB
    __shared__ float xl[16][DIN + 4];
    int tid = threadIdx.x;
    {
        const float4* Wv = (const float4*)W1;
        float4* Wd = (float4*)Wl;
        Wd[tid] = Wv[tid];
        Wd[tid + 256] = Wv[tid + 256];
    }
    int lane = tid & 63, w = tid >> 6;
    int g = lane >> 4, c = lane & 15;
    for (int sub = 0; sub < 4; sub++) {
        int tb = blockIdx.x * 64 + sub * 16;
        __syncthreads();
        if (tid < 128) {
            int idx = tid * 4;
            int row = idx / DIN, ck = idx % DIN;
            float4 v = {0.f, 0.f, 0.f, 0.f};
            if (tb + row < n)
                v = *(const float4*)&x[(size_t)(tb + row) * DIN + ck];
            *(float4*)&xl[row][ck] = v;
        }
        __syncthreads();
        int node = tb + w * 4 + g;
        const float* xr = xl[w * 4 + g];
        float4 acc = {0.f, 0.f, 0.f, 0.f};
        #pragma unroll
        for (int k = 0; k < DIN; k++) {
            float xv = xr[k];
            float4 wv = *(const float4*)&Wl[k * DH + c * 4];
            acc.x += xv * wv.x; acc.y += xv * wv.y; acc.z += xv * wv.z; acc.w += xv * wv.w;
        }
        if (node < n) {
            float di = dinv[node];
            ushort4 o;
            o.x = f2bf(acc.x * di); o.y = f2bf(acc.y * di);
            o.z = f2bf(acc.z * di); o.w = f2bf(acc.w * di);
            *(ushort4*)&hp[(size_t)node * DH + c * 4] = o;
        }
    }
}

// h2' = (relu(out1_bf16) @ W2) * dinv[node], bf16 out; 64 nodes/block
__global__ void __launch_bounds__(256) gemm2_k(
        const u16* __restrict__ io, const float* __restrict__ W2,
        const float* __restrict__ dinv, u16* __restrict__ hp, int n) {
    __shared__ float Wl[DH * DH];            // 16 KB
    __shared__ float xl[16][DH + 4];
    int tid = threadIdx.x;
    {
        const float4* Wv = (const float4*)W2;
        float4* Wd = (float4*)Wl;
        #pragma unroll
        for (int r = 0; r < 4; r++) Wd[tid + 256 * r] = Wv[tid + 256 * r];
    }
    int lane = tid & 63, w = tid >> 6;
    int g = lane >> 4, c = lane & 15;
    for (int sub = 0; sub < 4; sub++) {
        int tb = blockIdx.x * 64 + sub * 16;
        __syncthreads();
        {
            int idx = tid * 4;
            int row = idx / DH, ck = idx % DH;
            float4 v = {0.f, 0.f, 0.f, 0.f};
            if (tb + row < n) {
                ushort4 u = *(const ushort4*)&io[(size_t)(tb + row) * DH + ck];
                v.x = fmaxf(bf2f(u.x), 0.f); v.y = fmaxf(bf2f(u.y), 0.f);
                v.z = fmaxf(bf2f(u.z), 0.f); v.w = fmaxf(bf2f(u.w), 0.f);
            }
            *(float4*)&xl[row][ck] = v;
        }
        __syncthreads();
        int node = tb + w * 4 + g;
        const float* xr = xl[w * 4 + g];
        float4 acc = {0.f, 0.f, 0.f, 0.f};
        #pragma unroll
        for (int k = 0; k < DH; k++) {
            float xv = xr[k];
            float4 wv = *(const float4*)&Wl[k * DH + c * 4];
            acc.x += xv * wv.x; acc.y += xv * wv.y; acc.z += xv * wv.z; acc.w += xv * wv.w;
        }
        if (node < n) {
            float di = dinv[node];
            ushort4 o;
            o.x = f2bf(acc.x * di); o.y = f2bf(acc.y * di);
            o.z = f2bf(acc.z * di); o.w = f2bf(acc.w * di);
            *(ushort4*)&hp[(size_t)node * DH + c * 4] = o;
        }
    }
}

// group-per-node edge sum: 16-lane group g owns node; c=lane&15 (4 cols, 8B).
// deg/start are per-group; loop bound is wave-uniform degmax so every __shfl
// executes with all lanes active. No cross-group reduction needed.
__device__ __forceinline__ float4 edge_sum_grp(const u16* __restrict__ hp,
                                               const int* __restrict__ col,
                                               int start, int deg, int g, int c) {
    // wave-uniform max degree over the 4 groups
    int dm = deg;
    dm = max(dm, __shfl_xor(dm, 16, 64));
    dm = max(dm, __shfl_xor(dm, 32, 64));
    float4 acc = {0.f, 0.f, 0.f, 0.f};
    for (int base = 0; base < dm; base += 16) {
        int cb = (base + c < deg) ? col[start + base + c] : 0;
        int rm = dm - base; if (rm > 16) rm = 16;
        for (int j = 0; j < rm; j += 2) {
            int s0 = __shfl(cb, (g << 4) | j, 64);
            int s1 = __shfl(cb, (g << 4) | (j + 1), 64);
            bool a0 = base + j < deg;
            bool a1 = base + j + 1 < deg;
            if (a0) {
                ushort4 v = *(const ushort4*)&hp[(size_t)s0 * DH + c * 4];
                acc.x += bf2f(v.x); acc.y += bf2f(v.y); acc.z += bf2f(v.z); acc.w += bf2f(v.w);
            }
            if (a1) {
                ushort4 v = *(const ushort4*)&hp[(size_t)s1 * DH + c * 4];
                acc.x += bf2f(v.x); acc.y += bf2f(v.y); acc.z += bf2f(v.z); acc.w += bf2f(v.w);
            }
        }
    }
    return acc;
}

// out1[d] = (h'[d] + sum_neighbors) * dinv[d] + bias  -> bf16
// wave = 4 nodes (consecutive) -> stores form one contiguous 512B run
__global__ void __launch_bounds__(256) agg_mid_k(
        const u16* __restrict__ hp, const int* __restrict__ rstart,
        const int* __restrict__ rend, const int* __restrict__ col,
        const float* __restrict__ dinv, const float* __restrict__ bias,
        u16* __restrict__ out, int N) {
    int lane = threadIdx.x & 63;
    int g = lane >> 4, c = lane & 15;
    int node = blockIdx.x * 16 + (threadIdx.x >> 6) * 4 + g;
    int start = 0, deg = 0;
    if (node < N) { start = rstart[node]; deg = rend[node] - start; }
    float4 acc = edge_sum_grp(hp, col, start, deg, g, c);
    if (node < N) {
        ushort4 sv = *(const ushort4*)&hp[(size_t)node * DH + c * 4];
        float4 b = *(const float4*)&bias[c * 4];
        float di = dinv[node];
        ushort4 o;
        o.x = f2bf((acc.x + bf2f(sv.x)) * di + b.x);
        o.y = f2bf((acc.y + bf2f(sv.y)) * di + b.y);
        o.z = f2bf((acc.z + bf2f(sv.z)) * di + b.z);
        o.w = f2bf((acc.w + bf2f(sv.w)) * di + b.w);
        *(ushort4*)&out[(size_t)node * DH + c * 4] = o;
    }
}

// fused layer-2 aggregation + head: y = sigmoid(relu(out2) . Wo + bo)
__global__ void __launch_bounds__(256) agg_head_k(
        const u16* __restrict__ hp, const int* __restrict__ rstart,
        const int* __restrict__ rend, const int* __restrict__ col,
        const float* __restrict__ dinv, const float* __restrict__ bias,
        const float* __restrict__ Wo, const float* __restrict__ bo,
        float* __restrict__ y, int N) {
    int lane = threadIdx.x & 63;
    int g = lane >> 4, c = lane & 15;
    int node = blockIdx.x * 16 + (threadIdx.x >> 6) * 4 + g;
    int start = 0, deg = 0;
    if (node < N) { start = rstart[node]; deg = rend[node] - start; }
    float4 acc = edge_sum_grp(hp, col, start, deg, g, c);
    // intra-group (16-lane) reduction only; all lanes participate in shfl
    float t = 0.f;
    if (node < N) {
        ushort4 sv = *(const ushort4*)&hp[(size_t)node * DH + c * 4];
        float4 b = *(const float4*)&bias[c * 4];
        float4 wo = *(const float4*)&Wo[c * 4];
        float di = dinv[node];
        t = fmaxf((acc.x + bf2f(sv.x)) * di + b.x, 0.f) * wo.x
          + fmaxf((acc.y + bf2f(sv.y)) * di + b.y, 0.f) * wo.y
          + fmaxf((acc.z + bf2f(sv.z)) * di + b.z, 0.f) * wo.z
          + fmaxf((acc.w + bf2f(sv.w)) * di + b.w, 0.f) * wo.w;
    }
    #pragma unroll
    for (int m = 1; m < 16; m <<= 1) t += __shfl_xor(t, m, 64);
    if (c == 0 && node < N) {
        float z = t + bo[0];
        y[node] = 1.f / (1.f + __expf(-z));
    }
}

extern "C" void kernel_launch(void* const* d_in, const int* in_sizes, int n_in,
                              void* d_out, int out_size, void* d_ws, size_t ws_size,
                              hipStream_t stream) {
    const float* x  = (const float*)d_in[0];
    const int*   ei = (const int*)d_in[1];
    const float* W1 = (const float*)d_in[2];
    const float* b1 = (const float*)d_in[3];
    const float* W2 = (const float*)d_in[4];
    const float* b2 = (const float*)d_in[5];
    const float* Wo = (const float*)d_in[6];
    const float* bo = (const float*)d_in[7];
    float* y = (float*)d_out;

    int N = in_sizes[0] / DIN;
    int E = in_sizes[1] / 2;
    int nbuck = ((N - 1) >> BSH) + 1;            // 391 for N=100k (<= MAXB)

    char* ws = (char*)d_ws;
    size_t off = 0;
    auto alloc = [&](size_t bytes) { char* p = ws + off; off += (bytes + 255) & ~(size_t)255; return p; };
    int*   gcnt   = (int*)alloc(MAXB * 4);
    int*   rstart = (int*)alloc((size_t)N * 4);
    int*   rend   = (int*)alloc((size_t)N * 4);
    float* dinv   = (float*)alloc((size_t)N * 4);
    int*   col    = (int*)alloc(((size_t)nbuck << CAPSH) * 4);   // ~12.8 MB
    size_t pair_b = ((size_t)nbuck << CAPSH) * 4;
    size_t hp_b   = (size_t)N * DH * 2;
    char*  bufA   = (char*)alloc(pair_b > hp_b ? pair_b : hp_b); // pairs / hp alias
    u16*   bufB   = (u16*)alloc(hp_b);                           // out1 bf16
    u16*   hp    = (u16*)bufA;
    u32*   pairs = (u32*)bufA;   // pairs dead before gemm1 writes hp

    int gN16 = (N + 15) / 16;
    int gN64 = (N + 63) / 64;

    hipMemsetAsync(gcnt, 0, (size_t)nbuck * 4, stream);
    binA_k<<<512, 256, 0, stream>>>(ei, gcnt, pairs, E, N, nbuck);
    csr_bucket_k<<<nbuck, 512, 0, stream>>>(pairs, gcnt, rstart, rend, col, dinv, N);

    // layer 1
    gemm1_k<<<gN64, 256, 0, stream>>>(x, W1, dinv, hp, N);
    agg_mid_k<<<gN16, 256, 0, stream>>>(hp, rstart, rend, col, dinv, b1, bufB, N);

    // layer 2 + fused head
    gemm2_k<<<gN64, 256, 0, stream>>>(bufB, W2, dinv, hp, N);
    agg_head_k<<<gN16, 256, 0, stream>>>(hp, rstart, rend, col, dinv, b2, Wo, bo, y, N);
}

// Round 11
// 219.972 us; speedup vs baseline: 1.3050x; 1.0861x over previous
//
#include <hip/hip_runtime.h>

#define DH 64
#define DIN 32
#define BSH 8                 // bucket = dst >> 8 (256-node ranges)
#define BNODES 256
#define MAXB 1024
#define CAPSH 13              // per-bucket capacity 8192 (avg fill ~4.1k, sigma ~64)
#define CAP (1 << CAPSH)

typedef unsigned short u16;
typedef unsigned int u32;

__device__ __forceinline__ float bf2f(u16 u) {
    union { u32 i; float f; } x; x.i = ((u32)u) << 16; return x.f;
}
__device__ __forceinline__ u16 f2bf(float f) {
    union { float f; u32 i; } x; x.f = f;
    u32 r = x.i + 0x7fff + ((x.i >> 16) & 1);    // round-to-nearest-even
    return (u16)(r >> 16);
}

// bin packed (src<<BSH | local_dst) into fixed-capacity bucket spans with
// per-(block,bucket) private sub-spans. Grid-stride granules.
// Edge layout (int32 vs int64) detected inline by wave 0.
__global__ void __launch_bounds__(256) binA_k(
        const int* __restrict__ ei, int* __restrict__ gcnt,
        u32* __restrict__ pairs, int E, int n, int nbuck) {
    __shared__ int lhist[MAXB];
    __shared__ int lbase[MAXB];
    __shared__ int smode;
    int t = threadIdx.x;
    if (t < 64) {   // int64 layout: odd 32-bit words are zero high-words
        int v = (2 * t + 1 < 2 * E) ? ei[2 * t + 1] : 0;
        unsigned long long b = __ballot(v != 0);
        if (t == 0) smode = (b != 0ULL) ? 1 : 0;
    }
    for (int b = t; b < nbuck; b += 256) lhist[b] = 0;
    __syncthreads();
    int m = smode;
    unsigned un = (unsigned)n;
    int q0 = blockIdx.x * 256 + t;
    int qs = gridDim.x * 256;

    // ---- phase 1: count this block's edges per bucket
    if (m && !(E & 3)) {                       // int32, 4 edges per int4
        const int4* d4 = (const int4*)(ei + E);
        for (int q = q0; q < (E >> 2); q += qs) {
            int4 d = d4[q];
            if ((unsigned)d.x < un) atomicAdd(&lhist[d.x >> BSH], 1);
            if ((unsigned)d.y < un) atomicAdd(&lhist[d.y >> BSH], 1);
            if ((unsigned)d.z < un) atomicAdd(&lhist[d.z >> BSH], 1);
            if ((unsigned)d.w < un) atomicAdd(&lhist[d.w >> BSH], 1);
        }
    } else if (!m && !(E & 1)) {               // int64, 2 edges per int4
        const int4* d4 = (const int4*)(ei + 2 * E);
        for (int q = q0; q < (E >> 1); q += qs) {
            int4 d = d4[q];
            if ((unsigned)d.x < un) atomicAdd(&lhist[d.x >> BSH], 1);
            if ((unsigned)d.z < un) atomicAdd(&lhist[d.z >> BSH], 1);
        }
    } else {
        const int* dstp = m ? (ei + E) : (ei + 2 * E);
        int stride = m ? 1 : 2;
        for (int e = q0; e < E; e += qs) {
            int d = dstp[(size_t)e * stride];
            if ((unsigned)d < un) atomicAdd(&lhist[d >> BSH], 1);
        }
    }
    __syncthreads();
    // ---- phase 2: reserve private spans
    for (int b = t; b < nbuck; b += 256) {
        int c = lhist[b];
        lbase[b] = c ? ((b << CAPSH) + atomicAdd(&gcnt[b], c)) : 0;
        lhist[b] = 0;                          // reuse as local cursor
    }
    __syncthreads();
    // ---- phase 3: scatter into private spans
    #define EMIT(S, D)                                                     \
        if ((unsigned)(D) < un) {                                          \
            int sv = ((unsigned)(S) < un) ? (S) : 0;                       \
            int bb = (D) >> BSH;                                           \
            int off = atomicAdd(&lhist[bb], 1);                            \
            int pos = lbase[bb] + off;                                     \
            if (pos < ((bb + 1) << CAPSH))                                 \
                pairs[pos] = ((u32)sv << BSH) | (u32)((D) & (BNODES - 1)); \
        }
    if (m && !(E & 3)) {
        const int4* s4 = (const int4*)ei;
        const int4* d4 = (const int4*)(ei + E);
        for (int q = q0; q < (E >> 2); q += qs) {
            int4 s = s4[q]; int4 d = d4[q];
            EMIT(s.x, d.x) EMIT(s.y, d.y) EMIT(s.z, d.z) EMIT(s.w, d.w)
        }
    } else if (!m && !(E & 1)) {
        const int4* s4 = (const int4*)ei;
        const int4* d4 = (const int4*)(ei + 2 * E);
        for (int q = q0; q < (E >> 1); q += qs) {
            int4 s = s4[q]; int4 d = d4[q];
            EMIT(s.x, d.x) EMIT(s.z, d.z)
        }
    } else {
        const int* srcp = ei;
        const int* dstp = m ? (ei + E) : (ei + 2 * E);
        int stride = m ? 1 : 2;
        for (int e = q0; e < E; e += qs) {
            int d = dstp[(size_t)e * stride];
            int s = srcp[(size_t)e * stride];
            EMIT(s, d)
        }
    }
    #undef EMIT
}

// one block (512 thr) per bucket: LDS per-node histogram + scan -> rstart/rend/dinv,
// then fill col within the bucket's span
__global__ void __launch_bounds__(512) csr_bucket_k(
        const u32* __restrict__ pairs, const int* __restrict__ gcnt,
        int* __restrict__ rstart, int* __restrict__ rend,
        int* __restrict__ col, float* __restrict__ dinv, int N) {
    __shared__ int cnt[BNODES];
    __shared__ int s[BNODES];
    int b = blockIdx.x, t = threadIdx.x;
    int base = b << CAPSH;
    int ec = gcnt[b]; if (ec > CAP) ec = CAP;
    int end = base + ec;
    if (t < BNODES) cnt[t] = 0;
    __syncthreads();
    for (int i = base + t; i < end; i += 512)
        atomicAdd(&cnt[pairs[i] & (BNODES - 1)], 1);
    __syncthreads();
    int v = (t < BNODES) ? cnt[t] : 0;
    if (t < BNODES) s[t] = v;
    __syncthreads();
    for (int off = 1; off < BNODES; off <<= 1) {
        int x = (t >= off && t < BNODES) ? s[t - off] : 0;
        __syncthreads();
        if (t < BNODES) s[t] += x;
        __syncthreads();
    }
    if (t < BNODES) {
        int excl = s[t] - v;
        int a = base + excl;
        int node = (b << BSH) + t;
        if (node < N) {
            rstart[node] = a;
            rend[node]   = a + v;
            dinv[node]   = rsqrtf((float)v + 1.0f);
        }
        cnt[t] = a;                            // cursor
    }
    __syncthreads();
    for (int i = base + t; i < end; i += 512) {
        u32 p = pairs[i];
        int pos = atomicAdd(&cnt[p & (BNODES - 1)], 1);
        col[pos] = (int)(p >> BSH);
    }
}

// h1' = (x @ W1) * dinv[node], bf16 out; 64 nodes/block (4 sub-tiles of 16)
__global__ void __launch_bounds__(256) gemm1_k(
        const float* __restrict__ x, const float* __restrict__ W1,
        const float* __restrict__ dinv, u16* __restrict__ hp, int n) {
    __shared__ float Wl[DIN * DH];           // 8 KB
    __shared__ float xl[16][DIN + 4];
    int tid = threadIdx.x;
    {
        const float4* Wv = (const float4*)W1;
        float4* Wd = (float4*)Wl;
        Wd[tid] = Wv[tid];
        Wd[tid + 256] = Wv[tid + 256];
    }
    int lane = tid & 63, w = tid >> 6;
    int g = lane >> 4, c = lane & 15;
    for (int sub = 0; sub < 4; sub++) {
        int tb = blockIdx.x * 64 + sub * 16;
        __syncthreads();
        if (tid < 128) {
            int idx = tid * 4;
            int row = idx / DIN, ck = idx % DIN;
            float4 v = {0.f, 0.f, 0.f, 0.f};
            if (tb + row < n)
                v = *(const float4*)&x[(size_t)(tb + row) * DIN + ck];
            *(float4*)&xl[row][ck] = v;
        }
        __syncthreads();
        int node = tb + w * 4 + g;
        const float* xr = xl[w * 4 + g];
        float4 acc = {0.f, 0.f, 0.f, 0.f};
        #pragma unroll
        for (int k = 0; k < DIN; k++) {
            float xv = xr[k];
            float4 wv = *(const float4*)&Wl[k * DH + c * 4];
            acc.x += xv * wv.x; acc.y += xv * wv.y; acc.z += xv * wv.z; acc.w += xv * wv.w;
        }
        if (node < n) {
            float di = dinv[node];
            ushort4 o;
            o.x = f2bf(acc.x * di); o.y = f2bf(acc.y * di);
            o.z = f2bf(acc.z * di); o.w = f2bf(acc.w * di);
            *(ushort4*)&hp[(size_t)node * DH + c * 4] = o;
        }
    }
}

// h2' = (relu(out1_bf16) @ W2) * dinv[node], bf16 out; 64 nodes/block
__global__ void __launch_bounds__(256) gemm2_k(
        const u16* __restrict__ io, const float* __restrict__ W2,
        const float* __restrict__ dinv, u16* __restrict__ hp, int n) {
    __shared__ float Wl[DH * DH];            // 16 KB
    __shared__ float xl[16][DH + 4];
    int tid = threadIdx.x;
    {
        const float4* Wv = (const float4*)W2;
        float4* Wd = (float4*)Wl;
        #pragma unroll
        for (int r = 0; r < 4; r++) Wd[tid + 256 * r] = Wv[tid + 256 * r];
    }
    int lane = tid & 63, w = tid >> 6;
    int g = lane >> 4, c = lane & 15;
    for (int sub = 0; sub < 4; sub++) {
        int tb = blockIdx.x * 64 + sub * 16;
        __syncthreads();
        {
            int idx = tid * 4;
            int row = idx / DH, ck = idx % DH;
            float4 v = {0.f, 0.f, 0.f, 0.f};
            if (tb + row < n) {
                ushort4 u = *(const ushort4*)&io[(size_t)(tb + row) * DH + ck];
                v.x = fmaxf(bf2f(u.x), 0.f); v.y = fmaxf(bf2f(u.y), 0.f);
                v.z = fmaxf(bf2f(u.z), 0.f); v.w = fmaxf(bf2f(u.w), 0.f);
            }
            *(float4*)&xl[row][ck] = v;
        }
        __syncthreads();
        int node = tb + w * 4 + g;
        const float* xr = xl[w * 4 + g];
        float4 acc = {0.f, 0.f, 0.f, 0.f};
        #pragma unroll
        for (int k = 0; k < DH; k++) {
            float xv = xr[k];
            float4 wv = *(const float4*)&Wl[k * DH + c * 4];
            acc.x += xv * wv.x; acc.y += xv * wv.y; acc.z += xv * wv.z; acc.w += xv * wv.w;
        }
        if (node < n) {
            float di = dinv[node];
            ushort4 o;
            o.x = f2bf(acc.x * di); o.y = f2bf(acc.y * di);
            o.z = f2bf(acc.z * di); o.w = f2bf(acc.w * di);
            *(ushort4*)&hp[(size_t)node * DH + c * 4] = o;
        }
    }
}

// group-per-node edge sum: 16-lane group g owns node; c=lane&15 (4 cols, 8B).
// 4-deep gather pipeline + next-chunk col prefetch; loop bound is wave-uniform
// degmax so every __shfl executes with all lanes active.
__device__ __forceinline__ float4 edge_sum_grp(const u16* __restrict__ hp,
                                               const int* __restrict__ col,
                                               int start, int deg, int g, int c) {
    int dm = deg;
    dm = max(dm, __shfl_xor(dm, 16, 64));
    dm = max(dm, __shfl_xor(dm, 32, 64));
    float4 acc = {0.f, 0.f, 0.f, 0.f};
    if (dm <= 0) return acc;
    int gl = g << 4;
    int cb = (c < deg) ? col[start + c] : 0;   // chunk 0 col slice
    for (int base = 0; base < dm; base += 16) {
        int nb = base + 16;
        int cbn = 0;
        if (nb < dm) cbn = (nb + c < deg) ? col[start + nb + c] : 0;  // prefetch next chunk
        int rm = dm - base; if (rm > 16) rm = 16;
        for (int j = 0; j < rm; j += 4) {
            int s0 = __shfl(cb, gl | j, 64);
            int s1 = __shfl(cb, gl | (j + 1), 64);
            int s2 = __shfl(cb, gl | (j + 2), 64);
            int s3 = __shfl(cb, gl | (j + 3), 64);
            bool a0 = base + j     < deg;
            bool a1 = base + j + 1 < deg;
            bool a2 = base + j + 2 < deg;
            bool a3 = base + j + 3 < deg;
            ushort4 v0, v1, v2, v3;
            if (a0) v0 = *(const ushort4*)&hp[(size_t)s0 * DH + c * 4];
            if (a1) v1 = *(const ushort4*)&hp[(size_t)s1 * DH + c * 4];
            if (a2) v2 = *(const ushort4*)&hp[(size_t)s2 * DH + c * 4];
            if (a3) v3 = *(const ushort4*)&hp[(size_t)s3 * DH + c * 4];
            if (a0) { acc.x += bf2f(v0.x); acc.y += bf2f(v0.y); acc.z += bf2f(v0.z); acc.w += bf2f(v0.w); }
            if (a1) { acc.x += bf2f(v1.x); acc.y += bf2f(v1.y); acc.z += bf2f(v1.z); acc.w += bf2f(v1.w); }
            if (a2) { acc.x += bf2f(v2.x); acc.y += bf2f(v2.y); acc.z += bf2f(v2.z); acc.w += bf2f(v2.w); }
            if (a3) { acc.x += bf2f(v3.x); acc.y += bf2f(v3.y); acc.z += bf2f(v3.z); acc.w += bf2f(v3.w); }
        }
        cb = cbn;
    }
    return acc;
}

// out1[d] = (h'[d] + sum_neighbors) * dinv[d] + bias  -> bf16
// wave = 4 consecutive nodes -> stores form one contiguous 512B run
__global__ void __launch_bounds__(256) agg_mid_k(
        const u16* __restrict__ hp, const int* __restrict__ rstart,
        const int* __restrict__ rend, const int* __restrict__ col,
        const float* __restrict__ dinv, const float* __restrict__ bias,
        u16* __restrict__ out, int N) {
    int lane = threadIdx.x & 63;
    int g = lane >> 4, c = lane & 15;
    int node = blockIdx.x * 16 + (threadIdx.x >> 6) * 4 + g;
    int start = 0, deg = 0;
    if (node < N) { start = rstart[node]; deg = rend[node] - start; }
    float4 acc = edge_sum_grp(hp, col, start, deg, g, c);
    if (node < N) {
        ushort4 sv = *(const ushort4*)&hp[(size_t)node * DH + c * 4];
        float4 b = *(const float4*)&bias[c * 4];
        float di = dinv[node];
        ushort4 o;
        o.x = f2bf((acc.x + bf2f(sv.x)) * di + b.x);
        o.y = f2bf((acc.y + bf2f(sv.y)) * di + b.y);
        o.z = f2bf((acc.z + bf2f(sv.z)) * di + b.z);
        o.w = f2bf((acc.w + bf2f(sv.w)) * di + b.w);
        *(ushort4*)&out[(size_t)node * DH + c * 4] = o;
    }
}

// fused layer-2 aggregation + head: y = sigmoid(relu(out2) . Wo + bo)
__global__ void __launch_bounds__(256) agg_head_k(
        const u16* __restrict__ hp, const int* __restrict__ rstart,
        const int* __restrict__ rend, const int* __restrict__ col,
        const float* __restrict__ dinv, const float* __restrict__ bias,
        const float* __restrict__ Wo, const float* __restrict__ bo,
        float* __restrict__ y, int N) {
    int lane = threadIdx.x & 63;
    int g = lane >> 4, c = lane & 15;
    int node = blockIdx.x * 16 + (threadIdx.x >> 6) * 4 + g;
    int start = 0, deg = 0;
    if (node < N) { start = rstart[node]; deg = rend[node] - start; }
    float4 acc = edge_sum_grp(hp, col, start, deg, g, c);
    float t = 0.f;
    if (node < N) {
        ushort4 sv = *(const ushort4*)&hp[(size_t)node * DH + c * 4];
        float4 b = *(const float4*)&bias[c * 4];
        float4 wo = *(const float4*)&Wo[c * 4];
        float di = dinv[node];
        t = fmaxf((acc.x + bf2f(sv.x)) * di + b.x, 0.f) * wo.x
          + fmaxf((acc.y + bf2f(sv.y)) * di + b.y, 0.f) * wo.y
          + fmaxf((acc.z + bf2f(sv.z)) * di + b.z, 0.f) * wo.z
          + fmaxf((acc.w + bf2f(sv.w)) * di + b.w, 0.f) * wo.w;
    }
    #pragma unroll
    for (int m = 1; m < 16; m <<= 1) t += __shfl_xor(t, m, 64);
    if (c == 0 && node < N) {
        float z = t + bo[0];
        y[node] = 1.f / (1.f + __expf(-z));
    }
}

extern "C" void kernel_launch(void* const* d_in, const int* in_sizes, int n_in,
                              void* d_out, int out_size, void* d_ws, size_t ws_size,
                              hipStream_t stream) {
    const float* x  = (const float*)d_in[0];
    const int*   ei = (const int*)d_in[1];
    const float* W1 = (const float*)d_in[2];
    const float* b1 = (const float*)d_in[3];
    const float* W2 = (const float*)d_in[4];
    const float* b2 = (const float*)d_in[5];
    const float* Wo = (const float*)d_in[6];
    const float* bo = (const float*)d_in[7];
    float* y = (float*)d_out;

    int N = in_sizes[0] / DIN;
    int E = in_sizes[1] / 2;
    int nbuck = ((N - 1) >> BSH) + 1;            // 391 for N=100k (<= MAXB)

    char* ws = (char*)d_ws;
    size_t off = 0;
    auto alloc = [&](size_t bytes) { char* p = ws + off; off += (bytes + 255) & ~(size_t)255; return p; };
    int*   gcnt   = (int*)alloc(MAXB * 4);
    int*   rstart = (int*)alloc((size_t)N * 4);
    int*   rend   = (int*)alloc((size_t)N * 4);
    float* dinv   = (float*)alloc((size_t)N * 4);
    int*   col    = (int*)alloc(((size_t)nbuck << CAPSH) * 4);   // ~12.8 MB
    size_t pair_b = ((size_t)nbuck << CAPSH) * 4;
    size_t hp_b   = (size_t)N * DH * 2;
    char*  bufA   = (char*)alloc(pair_b > hp_b ? pair_b : hp_b); // pairs / hp alias
    u16*   bufB   = (u16*)alloc(hp_b);                           // out1 bf16
    u16*   hp    = (u16*)bufA;
    u32*   pairs = (u32*)bufA;   // pairs dead before gemm1 writes hp

    int gN16 = (N + 15) / 16;
    int gN64 = (N + 63) / 64;

    hipMemsetAsync(gcnt, 0, (size_t)nbuck * 4, stream);
    binA_k<<<768, 256, 0, stream>>>(ei, gcnt, pairs, E, N, nbuck);
    csr_bucket_k<<<nbuck, 512, 0, stream>>>(pairs, gcnt, rstart, rend, col, dinv, N);

    // layer 1
    gemm1_k<<<gN64, 256, 0, stream>>>(x, W1, dinv, hp, N);
    agg_mid_k<<<gN16, 256, 0, stream>>>(hp, rstart, rend, col, dinv, b1, bufB, N);

    // layer 2 + fused head
    gemm2_k<<<gN64, 256, 0, stream>>>(bufB, W2, dinv, hp, N);
    agg_head_k<<<gN16, 256, 0, stream>>>(hp, rstart, rend, col, dinv, b2, Wo, bo, y, N);
}

// Round 12
// 207.650 us; speedup vs baseline: 1.3824x; 1.0593x over previous
//
#include <hip/hip_runtime.h>

#define DH 64
#define DIN 32
#define BSH 8                 // bucket = dst >> 8 (256-node ranges)
#define BNODES 256
#define MAXB 1024
#define CAPSH 13              // per-bucket capacity 8192 (avg fill ~4.1k, sigma ~64)
#define CAP (1 << CAPSH)

typedef unsigned short u16;
typedef unsigned int u32;

__device__ __forceinline__ float bf2f(u16 u) {
    union { u32 i; float f; } x; x.i = ((u32)u) << 16; return x.f;
}
__device__ __forceinline__ u16 f2bf(float f) {
    union { float f; u32 i; } x; x.f = f;
    u32 r = x.i + 0x7fff + ((x.i >> 16) & 1);    // round-to-nearest-even
    return (u16)(r >> 16);
}

// bin packed (src<<BSH | local_dst) into fixed-capacity bucket spans with
// per-(block,bucket) private sub-spans. Grid-stride granules.
// Edge layout (int32 vs int64) detected inline by wave 0.
__global__ void __launch_bounds__(256) binA_k(
        const int* __restrict__ ei, int* __restrict__ gcnt,
        u32* __restrict__ pairs, int E, int n, int nbuck) {
    __shared__ int lhist[MAXB];
    __shared__ int lbase[MAXB];
    __shared__ int smode;
    int t = threadIdx.x;
    if (t < 64) {   // int64 layout: odd 32-bit words are zero high-words
        int v = (2 * t + 1 < 2 * E) ? ei[2 * t + 1] : 0;
        unsigned long long b = __ballot(v != 0);
        if (t == 0) smode = (b != 0ULL) ? 1 : 0;
    }
    for (int b = t; b < nbuck; b += 256) lhist[b] = 0;
    __syncthreads();
    int m = smode;
    unsigned un = (unsigned)n;
    int q0 = blockIdx.x * 256 + t;
    int qs = gridDim.x * 256;

    // ---- phase 1: count this block's edges per bucket
    if (m && !(E & 3)) {                       // int32, 4 edges per int4
        const int4* d4 = (const int4*)(ei + E);
        for (int q = q0; q < (E >> 2); q += qs) {
            int4 d = d4[q];
            if ((unsigned)d.x < un) atomicAdd(&lhist[d.x >> BSH], 1);
            if ((unsigned)d.y < un) atomicAdd(&lhist[d.y >> BSH], 1);
            if ((unsigned)d.z < un) atomicAdd(&lhist[d.z >> BSH], 1);
            if ((unsigned)d.w < un) atomicAdd(&lhist[d.w >> BSH], 1);
        }
    } else if (!m && !(E & 1)) {               // int64, 2 edges per int4
        const int4* d4 = (const int4*)(ei + 2 * E);
        for (int q = q0; q < (E >> 1); q += qs) {
            int4 d = d4[q];
            if ((unsigned)d.x < un) atomicAdd(&lhist[d.x >> BSH], 1);
            if ((unsigned)d.z < un) atomicAdd(&lhist[d.z >> BSH], 1);
        }
    } else {
        const int* dstp = m ? (ei + E) : (ei + 2 * E);
        int stride = m ? 1 : 2;
        for (int e = q0; e < E; e += qs) {
            int d = dstp[(size_t)e * stride];
            if ((unsigned)d < un) atomicAdd(&lhist[d >> BSH], 1);
        }
    }
    __syncthreads();
    // ---- phase 2: reserve private spans
    for (int b = t; b < nbuck; b += 256) {
        int c = lhist[b];
        lbase[b] = c ? ((b << CAPSH) + atomicAdd(&gcnt[b], c)) : 0;
        lhist[b] = 0;                          // reuse as local cursor
    }
    __syncthreads();
    // ---- phase 3: scatter into private spans
    #define EMIT(S, D)                                                     \
        if ((unsigned)(D) < un) {                                          \
            int sv = ((unsigned)(S) < un) ? (S) : 0;                       \
            int bb = (D) >> BSH;                                           \
            int off = atomicAdd(&lhist[bb], 1);                            \
            int pos = lbase[bb] + off;                                     \
            if (pos < ((bb + 1) << CAPSH))                                 \
                pairs[pos] = ((u32)sv << BSH) | (u32)((D) & (BNODES - 1)); \
        }
    if (m && !(E & 3)) {
        const int4* s4 = (const int4*)ei;
        const int4* d4 = (const int4*)(ei + E);
        for (int q = q0; q < (E >> 2); q += qs) {
            int4 s = s4[q]; int4 d = d4[q];
            EMIT(s.x, d.x) EMIT(s.y, d.y) EMIT(s.z, d.z) EMIT(s.w, d.w)
        }
    } else if (!m && !(E & 1)) {
        const int4* s4 = (const int4*)ei;
        const int4* d4 = (const int4*)(ei + 2 * E);
        for (int q = q0; q < (E >> 1); q += qs) {
            int4 s = s4[q]; int4 d = d4[q];
            EMIT(s.x, d.x) EMIT(s.z, d.z)
        }
    } else {
        const int* srcp = ei;
        const int* dstp = m ? (ei + E) : (ei + 2 * E);
        int stride = m ? 1 : 2;
        for (int e = q0; e < E; e += qs) {
            int d = dstp[(size_t)e * stride];
            int s = srcp[(size_t)e * stride];
            EMIT(s, d)
        }
    }
    #undef EMIT
}

// one block (512 thr) per bucket: LDS per-node histogram + scan -> rstart/rend/dinv,
// then fill col within the bucket's span
__global__ void __launch_bounds__(512) csr_bucket_k(
        const u32* __restrict__ pairs, const int* __restrict__ gcnt,
        int* __restrict__ rstart, int* __restrict__ rend,
        int* __restrict__ col, float* __restrict__ dinv, int N) {
    __shared__ int cnt[BNODES];
    __shared__ int s[BNODES];
    int b = blockIdx.x, t = threadIdx.x;
    int base = b << CAPSH;
    int ec = gcnt[b]; if (ec > CAP) ec = CAP;
    int end = base + ec;
    if (t < BNODES) cnt[t] = 0;
    __syncthreads();
    for (int i = base + t; i < end; i += 512)
        atomicAdd(&cnt[pairs[i] & (BNODES - 1)], 1);
    __syncthreads();
    int v = (t < BNODES) ? cnt[t] : 0;
    if (t < BNODES) s[t] = v;
    __syncthreads();
    for (int off = 1; off < BNODES; off <<= 1) {
        int x = (t >= off && t < BNODES) ? s[t - off] : 0;
        __syncthreads();
        if (t < BNODES) s[t] += x;
        __syncthreads();
    }
    if (t < BNODES) {
        int excl = s[t] - v;
        int a = base + excl;
        int node = (b << BSH) + t;
        if (node < N) {
            rstart[node] = a;
            rend[node]   = a + v;
            dinv[node]   = rsqrtf((float)v + 1.0f);
        }
        cnt[t] = a;                            // cursor
    }
    __syncthreads();
    for (int i = base + t; i < end; i += 512) {
        u32 p = pairs[i];
        int pos = atomicAdd(&cnt[p & (BNODES - 1)], 1);
        col[pos] = (int)(p >> BSH);
    }
}

// h1' = (x @ W1) * dinv[node], bf16 out; 64 nodes/block (4 sub-tiles of 16)
__global__ void __launch_bounds__(256) gemm1_k(
        const float* __restrict__ x, const float* __restrict__ W1,
        const float* __restrict__ dinv, u16* __restrict__ hp, int n) {
    __shared__ float Wl[DIN * DH];           // 8 KB
    __shared__ float xl[16][DIN + 4];
    int tid = threadIdx.x;
    {
        const float4* Wv = (const float4*)W1;
        float4* Wd = (float4*)Wl;
        Wd[tid] = Wv[tid];
        Wd[tid + 256] = Wv[tid + 256];
    }
    int lane = tid & 63, w = tid >> 6;
    int g = lane >> 4, c = lane & 15;
    for (int sub = 0; sub < 4; sub++) {
        int tb = blockIdx.x * 64 + sub * 16;
        __syncthreads();
        if (tid < 128) {
            int idx = tid * 4;
            int row = idx / DIN, ck = idx % DIN;
            float4 v = {0.f, 0.f, 0.f, 0.f};
            if (tb + row < n)
                v = *(const float4*)&x[(size_t)(tb + row) * DIN + ck];
            *(float4*)&xl[row][ck] = v;
        }
        __syncthreads();
        int node = tb + w * 4 + g;
        const float* xr = xl[w * 4 + g];
        float4 acc = {0.f, 0.f, 0.f, 0.f};
        #pragma unroll
        for (int k = 0; k < DIN; k++) {
            float xv = xr[k];
            float4 wv = *(const float4*)&Wl[k * DH + c * 4];
            acc.x += xv * wv.x; acc.y += xv * wv.y; acc.z += xv * wv.z; acc.w += xv * wv.w;
        }
        if (node < n) {
            float di = dinv[node];
            ushort4 o;
            o.x = f2bf(acc.x * di); o.y = f2bf(acc.y * di);
            o.z = f2bf(acc.z * di); o.w = f2bf(acc.w * di);
            *(ushort4*)&hp[(size_t)node * DH + c * 4] = o;
        }
    }
}

// group-per-node edge sum: 16-lane group g owns node; c=lane&15 (4 cols, 8B).
// 4-deep gather pipeline + next-chunk col prefetch; loop bound is wave-uniform
// degmax so every __shfl executes with all lanes active.
__device__ __forceinline__ float4 edge_sum_grp(const u16* __restrict__ hp,
                                               const int* __restrict__ col,
                                               int start, int deg, int g, int c) {
    int dm = deg;
    dm = max(dm, __shfl_xor(dm, 16, 64));
    dm = max(dm, __shfl_xor(dm, 32, 64));
    float4 acc = {0.f, 0.f, 0.f, 0.f};
    if (dm <= 0) return acc;
    int gl = g << 4;
    int cb = (c < deg) ? col[start + c] : 0;   // chunk 0 col slice
    for (int base = 0; base < dm; base += 16) {
        int nb = base + 16;
        int cbn = 0;
        if (nb < dm) cbn = (nb + c < deg) ? col[start + nb + c] : 0;  // prefetch next chunk
        int rm = dm - base; if (rm > 16) rm = 16;
        for (int j = 0; j < rm; j += 4) {
            int s0 = __shfl(cb, gl | j, 64);
            int s1 = __shfl(cb, gl | (j + 1), 64);
            int s2 = __shfl(cb, gl | (j + 2), 64);
            int s3 = __shfl(cb, gl | (j + 3), 64);
            bool a0 = base + j     < deg;
            bool a1 = base + j + 1 < deg;
            bool a2 = base + j + 2 < deg;
            bool a3 = base + j + 3 < deg;
            ushort4 v0, v1, v2, v3;
            if (a0) v0 = *(const ushort4*)&hp[(size_t)s0 * DH + c * 4];
            if (a1) v1 = *(const ushort4*)&hp[(size_t)s1 * DH + c * 4];
            if (a2) v2 = *(const ushort4*)&hp[(size_t)s2 * DH + c * 4];
            if (a3) v3 = *(const ushort4*)&hp[(size_t)s3 * DH + c * 4];
            if (a0) { acc.x += bf2f(v0.x); acc.y += bf2f(v0.y); acc.z += bf2f(v0.z); acc.w += bf2f(v0.w); }
            if (a1) { acc.x += bf2f(v1.x); acc.y += bf2f(v1.y); acc.z += bf2f(v1.z); acc.w += bf2f(v1.w); }
            if (a2) { acc.x += bf2f(v2.x); acc.y += bf2f(v2.y); acc.z += bf2f(v2.z); acc.w += bf2f(v2.w); }
            if (a3) { acc.x += bf2f(v3.x); acc.y += bf2f(v3.y); acc.z += bf2f(v3.z); acc.w += bf2f(v3.w); }
        }
        cb = cbn;
    }
    return acc;
}

// FUSED layer-1 aggregation + layer-2 GEMM:
// out1 = (h1'[d] + sum_neighbors)*dinv + b1 ; h2' = (relu(out1) @ W2) * dinv -> bf16
// out1 row round-trips through a wave-private LDS tile (no barrier: same wave
// produces and consumes; +4 row pad puts the 4 groups' broadcast reads on
// distinct banks). gemm2's FMA work fills the gather's idle VALU slots.
__global__ void __launch_bounds__(256) agg_gemm_k(
        const u16* __restrict__ hp, const int* __restrict__ rstart,
        const int* __restrict__ rend, const int* __restrict__ col,
        const float* __restrict__ dinv, const float* __restrict__ b1,
        const float* __restrict__ W2, u16* __restrict__ hp2, int N) {
    __shared__ float Wl[DH * DH];            // 16 KB
    __shared__ float xs[4][4][DH + 4];       // wave-private rows, 68-float stride
    int tid = threadIdx.x;
    {
        const float4* Wv = (const float4*)W2;
        float4* Wd = (float4*)Wl;
        #pragma unroll
        for (int r = 0; r < 4; r++) Wd[tid + 256 * r] = Wv[tid + 256 * r];
    }
    __syncthreads();
    int lane = tid & 63, w = tid >> 6;
    int g = lane >> 4, c = lane & 15;
    int node = blockIdx.x * 16 + w * 4 + g;
    int start = 0, deg = 0;
    if (node < N) { start = rstart[node]; deg = rend[node] - start; }
    float4 acc = edge_sum_grp(hp, col, start, deg, g, c);
    float di = (node < N) ? dinv[node] : 0.f;
    float4 o = {0.f, 0.f, 0.f, 0.f};
    if (node < N) {
        ushort4 sv = *(const ushort4*)&hp[(size_t)node * DH + c * 4];
        float4 b = *(const float4*)&b1[c * 4];
        o.x = fmaxf((acc.x + bf2f(sv.x)) * di + b.x, 0.f);
        o.y = fmaxf((acc.y + bf2f(sv.y)) * di + b.y, 0.f);
        o.z = fmaxf((acc.z + bf2f(sv.z)) * di + b.z, 0.f);
        o.w = fmaxf((acc.w + bf2f(sv.w)) * di + b.w, 0.f);
    }
    *(float4*)&xs[w][g][c * 4] = o;          // 68*4=272B row stride, 16B-aligned
    // same-wave consume; compiler inserts the lgkmcnt wait
    const float* xr = xs[w][g];
    float4 a2 = {0.f, 0.f, 0.f, 0.f};
    #pragma unroll
    for (int k = 0; k < DH; k++) {
        float xv = xr[k];
        float4 wv = *(const float4*)&Wl[k * DH + c * 4];
        a2.x += xv * wv.x; a2.y += xv * wv.y; a2.z += xv * wv.z; a2.w += xv * wv.w;
    }
    if (node < N) {
        ushort4 po;
        po.x = f2bf(a2.x * di); po.y = f2bf(a2.y * di);
        po.z = f2bf(a2.z * di); po.w = f2bf(a2.w * di);
        *(ushort4*)&hp2[(size_t)node * DH + c * 4] = po;
    }
}

// fused layer-2 aggregation + head: y = sigmoid(relu(out2) . Wo + bo)
__global__ void __launch_bounds__(256) agg_head_k(
        const u16* __restrict__ hp, const int* __restrict__ rstart,
        const int* __restrict__ rend, const int* __restrict__ col,
        const float* __restrict__ dinv, const float* __restrict__ bias,
        const float* __restrict__ Wo, const float* __restrict__ bo,
        float* __restrict__ y, int N) {
    int lane = threadIdx.x & 63;
    int g = lane >> 4, c = lane & 15;
    int node = blockIdx.x * 16 + (threadIdx.x >> 6) * 4 + g;
    int start = 0, deg = 0;
    if (node < N) { start = rstart[node]; deg = rend[node] - start; }
    float4 acc = edge_sum_grp(hp, col, start, deg, g, c);
    float t = 0.f;
    if (node < N) {
        ushort4 sv = *(const ushort4*)&hp[(size_t)node * DH + c * 4];
        float4 b = *(const float4*)&bias[c * 4];
        float4 wo = *(const float4*)&Wo[c * 4];
        float di = dinv[node];
        t = fmaxf((acc.x + bf2f(sv.x)) * di + b.x, 0.f) * wo.x
          + fmaxf((acc.y + bf2f(sv.y)) * di + b.y, 0.f) * wo.y
          + fmaxf((acc.z + bf2f(sv.z)) * di + b.z, 0.f) * wo.z
          + fmaxf((acc.w + bf2f(sv.w)) * di + b.w, 0.f) * wo.w;
    }
    #pragma unroll
    for (int m = 1; m < 16; m <<= 1) t += __shfl_xor(t, m, 64);
    if (c == 0 && node < N) {
        float z = t + bo[0];
        y[node] = 1.f / (1.f + __expf(-z));
    }
}

extern "C" void kernel_launch(void* const* d_in, const int* in_sizes, int n_in,
                              void* d_out, int out_size, void* d_ws, size_t ws_size,
                              hipStream_t stream) {
    const float* x  = (const float*)d_in[0];
    const int*   ei = (const int*)d_in[1];
    const float* W1 = (const float*)d_in[2];
    const float* b1 = (const float*)d_in[3];
    const float* W2 = (const float*)d_in[4];
    const float* b2 = (const float*)d_in[5];
    const float* Wo = (const float*)d_in[6];
    const float* bo = (const float*)d_in[7];
    float* y = (float*)d_out;

    int N = in_sizes[0] / DIN;
    int E = in_sizes[1] / 2;
    int nbuck = ((N - 1) >> BSH) + 1;            // 391 for N=100k (<= MAXB)

    char* ws = (char*)d_ws;
    size_t off = 0;
    auto alloc = [&](size_t bytes) { char* p = ws + off; off += (bytes + 255) & ~(size_t)255; return p; };
    int*   gcnt   = (int*)alloc(MAXB * 4);
    int*   rstart = (int*)alloc((size_t)N * 4);
    int*   rend   = (int*)alloc((size_t)N * 4);
    float* dinv   = (float*)alloc((size_t)N * 4);
    int*   col    = (int*)alloc(((size_t)nbuck << CAPSH) * 4);   // ~12.8 MB
    size_t pair_b = ((size_t)nbuck << CAPSH) * 4;
    size_t hp_b   = (size_t)N * DH * 2;
    char*  bufA   = (char*)alloc(pair_b > hp_b ? pair_b : hp_b); // pairs / h1' alias
    u16*   bufB   = (u16*)alloc(hp_b);                           // h2' bf16
    u16*   hp    = (u16*)bufA;
    u32*   pairs = (u32*)bufA;   // pairs dead before gemm1 writes hp

    int gN16 = (N + 15) / 16;
    int gN64 = (N + 63) / 64;

    hipMemsetAsync(gcnt, 0, (size_t)nbuck * 4, stream);
    binA_k<<<768, 256, 0, stream>>>(ei, gcnt, pairs, E, N, nbuck);
    csr_bucket_k<<<nbuck, 512, 0, stream>>>(pairs, gcnt, rstart, rend, col, dinv, N);

    // layer 1 transform
    gemm1_k<<<gN64, 256, 0, stream>>>(x, W1, dinv, hp, N);
    // layer-1 aggregation fused with layer-2 transform: bufB = h2'
    agg_gemm_k<<<gN16, 256, 0, stream>>>(hp, rstart, rend, col, dinv, b1, W2, bufB, N);
    // layer-2 aggregation fused with head
    agg_head_k<<<gN16, 256, 0, stream>>>(bufB, rstart, rend, col, dinv, b2, Wo, bo, y, N);
}

// Round 13
// 202.574 us; speedup vs baseline: 1.4171x; 1.0251x over previous
//
#include <hip/hip_runtime.h>

#define DH 64
#define DIN 32
#define BSH 8                 // bucket = dst >> 8 (256-node ranges)
#define BNODES 256
#define MAXB 1024
#define CAPSH 13              // per-bucket capacity 8192 (avg fill ~4.1k, sigma ~64)
#define CAP (1 << CAPSH)

typedef unsigned short u16;
typedef unsigned int u32;

__device__ __forceinline__ float bf2f(u16 u) {
    union { u32 i; float f; } x; x.i = ((u32)u) << 16; return x.f;
}
__device__ __forceinline__ u16 f2bf(float f) {
    union { float f; u32 i; } x; x.f = f;
    u32 r = x.i + 0x7fff + ((x.i >> 16) & 1);    // round-to-nearest-even
    return (u16)(r >> 16);
}

// bin packed (src<<BSH | local_dst) into fixed-capacity bucket spans with
// per-(block,bucket) private sub-spans. Grid-stride granules.
// Edge layout (int32 vs int64) detected inline by wave 0.
__global__ void __launch_bounds__(256) binA_k(
        const int* __restrict__ ei, int* __restrict__ gcnt,
        u32* __restrict__ pairs, int E, int n, int nbuck) {
    __shared__ int lhist[MAXB];
    __shared__ int lbase[MAXB];
    __shared__ int smode;
    int t = threadIdx.x;
    if (t < 64) {   // int64 layout: odd 32-bit words are zero high-words
        int v = (2 * t + 1 < 2 * E) ? ei[2 * t + 1] : 0;
        unsigned long long b = __ballot(v != 0);
        if (t == 0) smode = (b != 0ULL) ? 1 : 0;
    }
    for (int b = t; b < nbuck; b += 256) lhist[b] = 0;
    __syncthreads();
    int m = smode;
    unsigned un = (unsigned)n;
    int q0 = blockIdx.x * 256 + t;
    int qs = gridDim.x * 256;

    // ---- phase 1: count this block's edges per bucket
    if (m && !(E & 3)) {                       // int32, 4 edges per int4
        const int4* d4 = (const int4*)(ei + E);
        for (int q = q0; q < (E >> 2); q += qs) {
            int4 d = d4[q];
            if ((unsigned)d.x < un) atomicAdd(&lhist[d.x >> BSH], 1);
            if ((unsigned)d.y < un) atomicAdd(&lhist[d.y >> BSH], 1);
            if ((unsigned)d.z < un) atomicAdd(&lhist[d.z >> BSH], 1);
            if ((unsigned)d.w < un) atomicAdd(&lhist[d.w >> BSH], 1);
        }
    } else if (!m && !(E & 1)) {               // int64, 2 edges per int4
        const int4* d4 = (const int4*)(ei + 2 * E);
        for (int q = q0; q < (E >> 1); q += qs) {
            int4 d = d4[q];
            if ((unsigned)d.x < un) atomicAdd(&lhist[d.x >> BSH], 1);
            if ((unsigned)d.z < un) atomicAdd(&lhist[d.z >> BSH], 1);
        }
    } else {
        const int* dstp = m ? (ei + E) : (ei + 2 * E);
        int stride = m ? 1 : 2;
        for (int e = q0; e < E; e += qs) {
            int d = dstp[(size_t)e * stride];
            if ((unsigned)d < un) atomicAdd(&lhist[d >> BSH], 1);
        }
    }
    __syncthreads();
    // ---- phase 2: reserve private spans
    for (int b = t; b < nbuck; b += 256) {
        int c = lhist[b];
        lbase[b] = c ? ((b << CAPSH) + atomicAdd(&gcnt[b], c)) : 0;
        lhist[b] = 0;                          // reuse as local cursor
    }
    __syncthreads();
    // ---- phase 3: scatter into private spans
    #define EMIT(S, D)                                                     \
        if ((unsigned)(D) < un) {                                          \
            int sv = ((unsigned)(S) < un) ? (S) : 0;                       \
            int bb = (D) >> BSH;                                           \
            int off = atomicAdd(&lhist[bb], 1);                            \
            int pos = lbase[bb] + off;                                     \
            if (pos < ((bb + 1) << CAPSH))                                 \
                pairs[pos] = ((u32)sv << BSH) | (u32)((D) & (BNODES - 1)); \
        }
    if (m && !(E & 3)) {
        const int4* s4 = (const int4*)ei;
        const int4* d4 = (const int4*)(ei + E);
        for (int q = q0; q < (E >> 2); q += qs) {
            int4 s = s4[q]; int4 d = d4[q];
            EMIT(s.x, d.x) EMIT(s.y, d.y) EMIT(s.z, d.z) EMIT(s.w, d.w)
        }
    } else if (!m && !(E & 1)) {
        const int4* s4 = (const int4*)ei;
        const int4* d4 = (const int4*)(ei + 2 * E);
        for (int q = q0; q < (E >> 1); q += qs) {
            int4 s = s4[q]; int4 d = d4[q];
            EMIT(s.x, d.x) EMIT(s.z, d.z)
        }
    } else {
        const int* srcp = ei;
        const int* dstp = m ? (ei + E) : (ei + 2 * E);
        int stride = m ? 1 : 2;
        for (int e = q0; e < E; e += qs) {
            int d = dstp[(size_t)e * stride];
            int s = srcp[(size_t)e * stride];
            EMIT(s, d)
        }
    }
    #undef EMIT
}

// one block (512 thr) per bucket: CSR build FUSED with gemm1.
// Invariant: bucket b's pairs span [b*32768, b*32768+32768) bytes of bufA is
// EXACTLY its 256 nodes' hp rows (256 * 128 B). Phase A/B consume pairs;
// after a barrier, phase C overwrites the span in place with h1' bf16.
__global__ void __launch_bounds__(512) csr_gemm_k(
        u32* __restrict__ pairs, const int* __restrict__ gcnt,
        int* __restrict__ rstart, int* __restrict__ rend,
        int* __restrict__ col, float* __restrict__ dinv,
        const float* __restrict__ x, const float* __restrict__ W1, int N) {
    __shared__ int cnt[BNODES];
    __shared__ int s[BNODES];
    __shared__ float dl[BNODES];
    __shared__ float Wl[DIN * DH];           // 8 KB
    __shared__ float xl[32][DIN + 4];        // 4.6 KB
    int b = blockIdx.x, t = threadIdx.x;
    int base = b << CAPSH;
    int ec = gcnt[b]; if (ec > CAP) ec = CAP;
    int end = base + ec;
    // W1 staging overlaps the histogram (512 float4 = 512 threads x 1)
    ((float4*)Wl)[t] = ((const float4*)W1)[t];
    if (t < BNODES) cnt[t] = 0;
    __syncthreads();
    // ---- phase A: per-node histogram
    for (int i = base + t; i < end; i += 512)
        atomicAdd(&cnt[pairs[i] & (BNODES - 1)], 1);
    __syncthreads();
    int v = (t < BNODES) ? cnt[t] : 0;
    if (t < BNODES) s[t] = v;
    __syncthreads();
    for (int off = 1; off < BNODES; off <<= 1) {
        int xsc = (t >= off && t < BNODES) ? s[t - off] : 0;
        __syncthreads();
        if (t < BNODES) s[t] += xsc;
        __syncthreads();
    }
    if (t < BNODES) {
        int excl = s[t] - v;
        int a = base + excl;
        int node = (b << BSH) + t;
        float di = rsqrtf((float)v + 1.0f);
        dl[t] = di;
        if (node < N) {
            rstart[node] = a;
            rend[node]   = a + v;
            dinv[node]   = di;
        }
        cnt[t] = a;                            // cursor
    }
    __syncthreads();
    // ---- phase B: fill col (consumes pairs)
    for (int i = base + t; i < end; i += 512) {
        u32 p = pairs[i];
        int pos = atomicAdd(&cnt[p & (BNODES - 1)], 1);
        col[pos] = (int)(p >> BSH);
    }
    __syncthreads();                           // pairs fully consumed
    // ---- phase C: h1' = (x @ W1) * dinv for this bucket's 256 nodes,
    // written over the (dead) pairs span: hp row of node nb0+r.
    u16* hp = (u16*)pairs;                     // device-global base; rows indexed by node
    int lane = t & 63, w = t >> 6;             // 8 waves
    int g = lane >> 4, c = lane & 15;
    for (int it = 0; it < 8; it++) {
        int nl0 = it * 32;                     // local node base (32 nodes/iter)
        __syncthreads();
        if (t < 256) {
            int idx = t * 4;
            int row = idx / DIN, ck = idx % DIN;
            int node = (b << BSH) + nl0 + row;
            float4 vx = {0.f, 0.f, 0.f, 0.f};
            if (node < N)
                vx = *(const float4*)&x[(size_t)node * DIN + ck];
            *(float4*)&xl[row][ck] = vx;
        }
        __syncthreads();
        int nl = nl0 + w * 4 + g;
        int node = (b << BSH) + nl;
        const float* xr = xl[nl - nl0];
        float4 acc = {0.f, 0.f, 0.f, 0.f};
        #pragma unroll
        for (int k = 0; k < DIN; k++) {
            float xv = xr[k];
            float4 wv = *(const float4*)&Wl[k * DH + c * 4];
            acc.x += xv * wv.x; acc.y += xv * wv.y; acc.z += xv * wv.z; acc.w += xv * wv.w;
        }
        if (node < N) {
            float di = dl[nl];
            ushort4 o;
            o.x = f2bf(acc.x * di); o.y = f2bf(acc.y * di);
            o.z = f2bf(acc.z * di); o.w = f2bf(acc.w * di);
            *(ushort4*)&hp[(size_t)node * DH + c * 4] = o;
        }
    }
}

// group-per-node edge sum: 16-lane group g owns node; c=lane&15 (4 cols, 8B).
// 8-deep gather pipeline + next-chunk col prefetch; loop bound is wave-uniform
// degmax so every __shfl executes with all lanes active.
__device__ __forceinline__ float4 edge_sum_grp(const u16* __restrict__ hp,
                                               const int* __restrict__ col,
                                               int start, int deg, int g, int c) {
    int dm = deg;
    dm = max(dm, __shfl_xor(dm, 16, 64));
    dm = max(dm, __shfl_xor(dm, 32, 64));
    float4 acc = {0.f, 0.f, 0.f, 0.f};
    if (dm <= 0) return acc;
    int gl = g << 4;
    int cb = (c < deg) ? col[start + c] : 0;   // chunk 0 col slice
    for (int base = 0; base < dm; base += 16) {
        int nb = base + 16;
        int cbn = 0;
        if (nb < dm) cbn = (nb + c < deg) ? col[start + nb + c] : 0;  // prefetch next chunk
        int rm = dm - base; if (rm > 16) rm = 16;
        for (int j = 0; j < rm; j += 8) {
            int s0 = __shfl(cb, gl | j, 64);
            int s1 = __shfl(cb, gl | (j + 1), 64);
            int s2 = __shfl(cb, gl | (j + 2), 64);
            int s3 = __shfl(cb, gl | (j + 3), 64);
            int s4 = __shfl(cb, gl | (j + 4), 64);
            int s5 = __shfl(cb, gl | (j + 5), 64);
            int s6 = __shfl(cb, gl | (j + 6), 64);
            int s7 = __shfl(cb, gl | (j + 7), 64);
            bool a0 = base + j     < deg;
            bool a1 = base + j + 1 < deg;
            bool a2 = base + j + 2 < deg;
            bool a3 = base + j + 3 < deg;
            bool a4 = base + j + 4 < deg;
            bool a5 = base + j + 5 < deg;
            bool a6 = base + j + 6 < deg;
            bool a7 = base + j + 7 < deg;
            ushort4 v0, v1, v2, v3, v4, v5, v6, v7;
            if (a0) v0 = *(const ushort4*)&hp[(size_t)s0 * DH + c * 4];
            if (a1) v1 = *(const ushort4*)&hp[(size_t)s1 * DH + c * 4];
            if (a2) v2 = *(const ushort4*)&hp[(size_t)s2 * DH + c * 4];
            if (a3) v3 = *(const ushort4*)&hp[(size_t)s3 * DH + c * 4];
            if (a4) v4 = *(const ushort4*)&hp[(size_t)s4 * DH + c * 4];
            if (a5) v5 = *(const ushort4*)&hp[(size_t)s5 * DH + c * 4];
            if (a6) v6 = *(const ushort4*)&hp[(size_t)s6 * DH + c * 4];
            if (a7) v7 = *(const ushort4*)&hp[(size_t)s7 * DH + c * 4];
            if (a0) { acc.x += bf2f(v0.x); acc.y += bf2f(v0.y); acc.z += bf2f(v0.z); acc.w += bf2f(v0.w); }
            if (a1) { acc.x += bf2f(v1.x); acc.y += bf2f(v1.y); acc.z += bf2f(v1.z); acc.w += bf2f(v1.w); }
            if (a2) { acc.x += bf2f(v2.x); acc.y += bf2f(v2.y); acc.z += bf2f(v2.z); acc.w += bf2f(v2.w); }
            if (a3) { acc.x += bf2f(v3.x); acc.y += bf2f(v3.y); acc.z += bf2f(v3.z); acc.w += bf2f(v3.w); }
            if (a4) { acc.x += bf2f(v4.x); acc.y += bf2f(v4.y); acc.z += bf2f(v4.z); acc.w += bf2f(v4.w); }
            if (a5) { acc.x += bf2f(v5.x); acc.y += bf2f(v5.y); acc.z += bf2f(v5.z); acc.w += bf2f(v5.w); }
            if (a6) { acc.x += bf2f(v6.x); acc.y += bf2f(v6.y); acc.z += bf2f(v6.z); acc.w += bf2f(v6.w); }
            if (a7) { acc.x += bf2f(v7.x); acc.y += bf2f(v7.y); acc.z += bf2f(v7.z); acc.w += bf2f(v7.w); }
        }
        cb = cbn;
    }
    return acc;
}

// FUSED layer-1 aggregation + layer-2 GEMM:
// out1 = (h1'[d] + sum_neighbors)*dinv + b1 ; h2' = (relu(out1) @ W2) * dinv -> bf16
__global__ void __launch_bounds__(256) agg_gemm_k(
        const u16* __restrict__ hp, const int* __restrict__ rstart,
        const int* __restrict__ rend, const int* __restrict__ col,
        const float* __restrict__ dinv, const float* __restrict__ b1,
        const float* __restrict__ W2, u16* __restrict__ hp2, int N) {
    __shared__ float Wl[DH * DH];            // 16 KB
    __shared__ float xs[4][4][DH + 4];       // wave-private rows, 68-float stride
    int tid = threadIdx.x;
    {
        const float4* Wv = (const float4*)W2;
        float4* Wd = (float4*)Wl;
        #pragma unroll
        for (int r = 0; r < 4; r++) Wd[tid + 256 * r] = Wv[tid + 256 * r];
    }
    __syncthreads();
    int lane = tid & 63, w = tid >> 6;
    int g = lane >> 4, c = lane & 15;
    int node = blockIdx.x * 16 + w * 4 + g;
    int start = 0, deg = 0;
    if (node < N) { start = rstart[node]; deg = rend[node] - start; }
    float4 acc = edge_sum_grp(hp, col, start, deg, g, c);
    float di = (node < N) ? dinv[node] : 0.f;
    float4 o = {0.f, 0.f, 0.f, 0.f};
    if (node < N) {
        ushort4 sv = *(const ushort4*)&hp[(size_t)node * DH + c * 4];
        float4 b = *(const float4*)&b1[c * 4];
        o.x = fmaxf((acc.x + bf2f(sv.x)) * di + b.x, 0.f);
        o.y = fmaxf((acc.y + bf2f(sv.y)) * di + b.y, 0.f);
        o.z = fmaxf((acc.z + bf2f(sv.z)) * di + b.z, 0.f);
        o.w = fmaxf((acc.w + bf2f(sv.w)) * di + b.w, 0.f);
    }
    *(float4*)&xs[w][g][c * 4] = o;          // same-wave produce/consume, no barrier
    const float* xr = xs[w][g];
    float4 a2 = {0.f, 0.f, 0.f, 0.f};
    #pragma unroll
    for (int k = 0; k < DH; k++) {
        float xv = xr[k];
        float4 wv = *(const float4*)&Wl[k * DH + c * 4];
        a2.x += xv * wv.x; a2.y += xv * wv.y; a2.z += xv * wv.z; a2.w += xv * wv.w;
    }
    if (node < N) {
        ushort4 po;
        po.x = f2bf(a2.x * di); po.y = f2bf(a2.y * di);
        po.z = f2bf(a2.z * di); po.w = f2bf(a2.w * di);
        *(ushort4*)&hp2[(size_t)node * DH + c * 4] = po;
    }
}

// fused layer-2 aggregation + head: y = sigmoid(relu(out2) . Wo + bo)
__global__ void __launch_bounds__(256) agg_head_k(
        const u16* __restrict__ hp, const int* __restrict__ rstart,
        const int* __restrict__ rend, const int* __restrict__ col,
        const float* __restrict__ dinv, const float* __restrict__ bias,
        const float* __restrict__ Wo, const float* __restrict__ bo,
        float* __restrict__ y, int N) {
    int lane = threadIdx.x & 63;
    int g = lane >> 4, c = lane & 15;
    int node = blockIdx.x * 16 + (threadIdx.x >> 6) * 4 + g;
    int start = 0, deg = 0;
    if (node < N) { start = rstart[node]; deg = rend[node] - start; }
    float4 acc = edge_sum_grp(hp, col, start, deg, g, c);
    float t = 0.f;
    if (node < N) {
        ushort4 sv = *(const ushort4*)&hp[(size_t)node * DH + c * 4];
        float4 b = *(const float4*)&bias[c * 4];
        float4 wo = *(const float4*)&Wo[c * 4];
        float di = dinv[node];
        t = fmaxf((acc.x + bf2f(sv.x)) * di + b.x, 0.f) * wo.x
          + fmaxf((acc.y + bf2f(sv.y)) * di + b.y, 0.f) * wo.y
          + fmaxf((acc.z + bf2f(sv.z)) * di + b.z, 0.f) * wo.z
          + fmaxf((acc.w + bf2f(sv.w)) * di + b.w, 0.f) * wo.w;
    }
    #pragma unroll
    for (int m = 1; m < 16; m <<= 1) t += __shfl_xor(t, m, 64);
    if (c == 0 && node < N) {
        float z = t + bo[0];
        y[node] = 1.f / (1.f + __expf(-z));
    }
}

extern "C" void kernel_launch(void* const* d_in, const int* in_sizes, int n_in,
                              void* d_out, int out_size, void* d_ws, size_t ws_size,
                              hipStream_t stream) {
    const float* x  = (const float*)d_in[0];
    const int*   ei = (const int*)d_in[1];
    const float* W1 = (const float*)d_in[2];
    const float* b1 = (const float*)d_in[3];
    const float* W2 = (const float*)d_in[4];
    const float* b2 = (const float*)d_in[5];
    const float* Wo = (const float*)d_in[6];
    const float* bo = (const float*)d_in[7];
    float* y = (float*)d_out;

    int N = in_sizes[0] / DIN;
    int E = in_sizes[1] / 2;
    int nbuck = ((N - 1) >> BSH) + 1;            // 391 for N=100k (<= MAXB)

    char* ws = (char*)d_ws;
    size_t off = 0;
    auto alloc = [&](size_t bytes) { char* p = ws + off; off += (bytes + 255) & ~(size_t)255; return p; };
    int*   gcnt   = (int*)alloc(MAXB * 4);
    int*   rstart = (int*)alloc((size_t)N * 4);
    int*   rend   = (int*)alloc((size_t)N * 4);
    float* dinv   = (float*)alloc((size_t)N * 4);
    int*   col    = (int*)alloc(((size_t)nbuck << CAPSH) * 4);   // ~12.8 MB
    size_t pair_b = ((size_t)nbuck << CAPSH) * 4;
    size_t hp_b   = (size_t)N * DH * 2;
    char*  bufA   = (char*)alloc(pair_b > hp_b ? pair_b : hp_b); // pairs / h1' alias (same spans!)
    u16*   bufB   = (u16*)alloc(hp_b);                           // h2' bf16
    u16*   hp    = (u16*)bufA;
    u32*   pairs = (u32*)bufA;

    int gN16 = (N + 15) / 16;

    hipMemsetAsync(gcnt, 0, (size_t)nbuck * 4, stream);
    binA_k<<<768, 256, 0, stream>>>(ei, gcnt, pairs, E, N, nbuck);
    // CSR build + layer-1 transform fused (pairs consumed, hp written in place)
    csr_gemm_k<<<nbuck, 512, 0, stream>>>(pairs, gcnt, rstart, rend, col, dinv, x, W1, N);
    // layer-1 aggregation fused with layer-2 transform: bufB = h2'
    agg_gemm_k<<<gN16, 256, 0, stream>>>(hp, rstart, rend, col, dinv, b1, W2, bufB, N);
    // layer-2 aggregation fused with head
    agg_head_k<<<gN16, 256, 0, stream>>>(bufB, rstart, rend, col, dinv, b2, Wo, bo, y, N);
}